// Round 1
// baseline (2375.416 us; speedup 1.0000x reference)
//
#include <hip/hip_runtime.h>
#include <cstdint>
#include <cstddef>

// Problem constants
#define BDIM 2
#define NTOK 4096
#define EDIM 1024
#define HEADS 16
#define HDIM 64
#define MROWS (BDIM * NTOK)   // 8192

// ---------------------------------------------------------------------------
// W_eff[o][i] = W[o][i] + 2 * sum_r B[o][r] * A[r][i]     (LoRA folded)
// ---------------------------------------------------------------------------
__global__ __launch_bounds__(256) void build_weff_kernel(
    const float* __restrict__ W, const float* __restrict__ A,
    const float* __restrict__ Bm, float* __restrict__ dst)
{
    int idx = blockIdx.x * 256 + threadIdx.x;      // over E*E
    int o = idx >> 10, i = idx & 1023;
    float s = 0.f;
#pragma unroll
    for (int r = 0; r < 8; ++r) s += Bm[o * 8 + r] * A[r * 1024 + i];
    dst[idx] = W[idx] + 2.0f * s;
}

// ---------------------------------------------------------------------------
// Stable counting sort of one batch row of bucket ids (values < 256).
// sidx[p] = original index of p-th smallest (ties by index = stable).
// grid.x = batch
// ---------------------------------------------------------------------------
__global__ __launch_bounds__(256) void sort_kernel(
    const int* __restrict__ wb, int* __restrict__ sidx)
{
    __shared__ int sb[NTOK];
    __shared__ int hist[256];
    __shared__ int base[256];
    int t = threadIdx.x;
    int b = blockIdx.x;
    const int* w = wb + b * NTOK;
    for (int i = t; i < NTOK; i += 256) sb[i] = w[i];
    hist[t] = 0;
    __syncthreads();
    for (int i = t; i < NTOK; i += 256) atomicAdd(&hist[sb[i]], 1);
    __syncthreads();
    if (t == 0) {
        int run = 0;
        for (int u = 0; u < 256; ++u) { base[u] = run; run += hist[u]; }
    }
    __syncthreads();
    // thread t places all elements of bucket t, scanning n ascending (stable)
    int pos = base[t];
    int* outp = sidx + b * NTOK;
    for (int n = 0; n < NTOK; ++n) {
        if (sb[n] == t) { outp[pos++] = n; }
    }
}

// ---------------------------------------------------------------------------
// fp32 GEMM (NT):  Y[m][o] = sum_i X[m][i] * W[o][i] + bias[o]
// X: [M x 1024] row-major, W: [1024 x 1024] row-major (o major), M = 8192.
// 128x128 tile / block(256), 8x8 per thread split 4+4 (stride-64) so LDS
// reads are b128 with only 2-way bank aliasing (free).
// ---------------------------------------------------------------------------
__global__ __launch_bounds__(256) void gemm_nt_kernel(
    const float* __restrict__ X, const float* __restrict__ W,
    const float* __restrict__ bias, float* __restrict__ Y)
{
    const int K = EDIM;
    __shared__ float sA[16][132];
    __shared__ float sB[16][132];
    int t = threadIdx.x;
    int n0 = blockIdx.x * 128;
    int m0 = blockIdx.y * 128;
    float acc[8][8] = {};
    int ta = (t & 15) * 4;   // rows ta..ta+3 and 64+ta..64+ta+3
    int tb = (t >> 4) * 4;   // cols tb..tb+3 and 64+tb..64+tb+3

    for (int kt = 0; kt < K; kt += 16) {
        __syncthreads();
#pragma unroll
        for (int it = 0; it < 2; ++it) {
            int idx = t + it * 256;          // 512 float4 per matrix tile
            int row = idx >> 2;
            int k4 = (idx & 3) * 4;
            float4 xv = *(const float4*)(X + (size_t)(m0 + row) * K + kt + k4);
            sA[k4 + 0][row] = xv.x; sA[k4 + 1][row] = xv.y;
            sA[k4 + 2][row] = xv.z; sA[k4 + 3][row] = xv.w;
            float4 wv = *(const float4*)(W + (size_t)(n0 + row) * K + kt + k4);
            sB[k4 + 0][row] = wv.x; sB[k4 + 1][row] = wv.y;
            sB[k4 + 2][row] = wv.z; sB[k4 + 3][row] = wv.w;
        }
        __syncthreads();
#pragma unroll
        for (int kk = 0; kk < 16; ++kk) {
            float4 a0 = *(const float4*)&sA[kk][ta];
            float4 a1 = *(const float4*)&sA[kk][64 + ta];
            float4 b0 = *(const float4*)&sB[kk][tb];
            float4 b1 = *(const float4*)&sB[kk][64 + tb];
            float av[8] = {a0.x, a0.y, a0.z, a0.w, a1.x, a1.y, a1.z, a1.w};
            float bv[8] = {b0.x, b0.y, b0.z, b0.w, b1.x, b1.y, b1.z, b1.w};
#pragma unroll
            for (int i = 0; i < 8; ++i)
#pragma unroll
                for (int j = 0; j < 8; ++j)
                    acc[i][j] += av[i] * bv[j];
        }
    }
#pragma unroll
    for (int i = 0; i < 8; ++i) {
        int rowm = m0 + ((i < 4) ? (ta + i) : (64 + ta + i - 4));
#pragma unroll
        for (int j4 = 0; j4 < 2; ++j4) {
            int col = n0 + ((j4 == 0) ? tb : (64 + tb));
            float4 o;
            o.x = acc[i][j4 * 4 + 0] + bias[col + 0];
            o.y = acc[i][j4 * 4 + 1] + bias[col + 1];
            o.z = acc[i][j4 * 4 + 2] + bias[col + 2];
            o.w = acc[i][j4 * 4 + 3] + bias[col + 3];
            *(float4*)(Y + (size_t)rowm * EDIM + col) = o;
        }
    }
}

// ---------------------------------------------------------------------------
// Chunked attention for one scale (chunk size C), fp32, online softmax.
// Thread = one sorted position p; block = 256 sorted rows of one (b,h).
// Keys staged in 64-row LDS slabs. Writes out[token] += (attn/l)/3.
// grid = (NTOK/256, B*H)
// ---------------------------------------------------------------------------
template <int C>
__global__ __launch_bounds__(256) void attn_kernel(
    const float* __restrict__ Q, const float* __restrict__ K,
    const float* __restrict__ V, const int* __restrict__ sidx,
    float* __restrict__ out)
{
    __shared__ float sK[64][64];
    __shared__ float sV[64][64];
    int t = threadIdx.x;
    int bh = blockIdx.y;
    int b = bh >> 4, h = bh & 15;
    const int* sx = sidx + b * NTOK;
    int p0 = blockIdx.x * 256;
    int p = p0 + t;
    int c = p / C;
    int wstart = (c == 0) ? 0 : (c - 1) * C;   // window of key sorted-positions
    int wend = (c + 1) * C;                    // chunk0: own chunk only (mask)
    int c0 = p0 / C;
    int c1 = (p0 + 255) / C;
    int kmin = (c0 > 0) ? (c0 - 1) * C : 0;    // block's union key range
    int kmax = (c1 + 1) * C;

    int r = sx[p];
    const float* qrow = Q + (size_t)(b * NTOK + r) * EDIM + h * HDIM;
    float4 q4[16], acc[16];
#pragma unroll
    for (int i = 0; i < 16; ++i) {
        q4[i] = ((const float4*)qrow)[i];
        acc[i] = make_float4(0.f, 0.f, 0.f, 0.f);
    }
    float m = -1e30f, l = 0.f;

    for (int ks = kmin; ks < kmax; ks += 64) {
        int nk = min(64, kmax - ks);
        __syncthreads();
        for (int idx = t; idx < nk * 16; idx += 256) {
            int j = idx >> 4, d4 = idx & 15;
            int tok = sx[ks + j];
            size_t rowo = (size_t)(b * NTOK + tok) * EDIM + h * HDIM;
            ((float4*)sK[j])[d4] = ((const float4*)(K + rowo))[d4];
            ((float4*)sV[j])[d4] = ((const float4*)(V + rowo))[d4];
        }
        __syncthreads();
        int jlo = max(ks, wstart) - ks;        // both multiples of 16
        int jhi = min(ks + nk, wend) - ks;
        for (int g = jlo; g < jhi; g += 16) {  // exact groups of 16 keys
            float s[16];
            float mu = -1e30f;
#pragma unroll
            for (int jj = 0; jj < 16; ++jj) {
                float sum = 0.f;
                const float4* kr = (const float4*)sK[g + jj];
#pragma unroll
                for (int i = 0; i < 16; ++i) {
                    float4 kv = kr[i];
                    sum += q4[i].x * kv.x + q4[i].y * kv.y +
                           q4[i].z * kv.z + q4[i].w * kv.w;
                }
                s[jj] = sum * 0.125f;          // / sqrt(64)
                mu = fmaxf(mu, s[jj]);
            }
            if (mu > m) {
                float alpha = __expf(m - mu);  // m=-1e30 first time -> 0
                l *= alpha;
#pragma unroll
                for (int i = 0; i < 16; ++i) {
                    acc[i].x *= alpha; acc[i].y *= alpha;
                    acc[i].z *= alpha; acc[i].w *= alpha;
                }
                m = mu;
            }
#pragma unroll
            for (int jj = 0; jj < 16; ++jj) {
                float pw = __expf(s[jj] - m);
                l += pw;
                const float4* vr = (const float4*)sV[g + jj];
#pragma unroll
                for (int i = 0; i < 16; ++i) {
                    float4 vv = vr[i];
                    acc[i].x += pw * vv.x; acc[i].y += pw * vv.y;
                    acc[i].z += pw * vv.z; acc[i].w += pw * vv.w;
                }
            }
        }
    }
    float inv = 1.0f / (3.0f * l);             // softmax denom + 3-scale avg
    float* orow = out + (size_t)(b * NTOK + r) * EDIM + h * HDIM;
#pragma unroll
    for (int i = 0; i < 16; ++i) {
        float4 o = ((float4*)orow)[i];
        o.x += acc[i].x * inv; o.y += acc[i].y * inv;
        o.z += acc[i].z * inv; o.w += acc[i].w * inv;
        ((float4*)orow)[i] = o;
    }
}

// ---------------------------------------------------------------------------
extern "C" void kernel_launch(void* const* d_in, const int* in_sizes, int n_in,
                              void* d_out, int out_size, void* d_ws, size_t ws_size,
                              hipStream_t stream)
{
    const float* x   = (const float*)d_in[0];
    const int*   wbc = (const int*)d_in[1];
    const int*   wbm = (const int*)d_in[2];
    const int*   wbf = (const int*)d_in[3];
    const float* Wq = (const float*)d_in[4],  *bq = (const float*)d_in[5];
    const float* Aq = (const float*)d_in[6],  *Bq = (const float*)d_in[7];
    const float* Wk = (const float*)d_in[8],  *bk = (const float*)d_in[9];
    const float* Ak = (const float*)d_in[10], *Bk = (const float*)d_in[11];
    const float* Wv = (const float*)d_in[12], *bv = (const float*)d_in[13];
    const float* Av = (const float*)d_in[14], *Bv = (const float*)d_in[15];
    const float* Wo = (const float*)d_in[16], *bo = (const float*)d_in[17];
    const float* Ao = (const float*)d_in[18], *Bo = (const float*)d_in[19];

    const size_t EE  = (size_t)EDIM * EDIM;        // 1,048,576
    const size_t BNE = (size_t)MROWS * EDIM;       // 8,388,608

    float* ws   = (float*)d_ws;
    float* weff = ws;                  // 4 * EE
    float* qb   = ws + 4 * EE;         // BNE
    float* kb   = qb + BNE;            // BNE
    float* vb   = kb + BNE;            // BNE
    float* ab   = vb + BNE;            // BNE (attention accumulator)
    int*   sidx = (int*)(ab + BNE);    // 3 * B * NTOK ints

    // attention accumulator must start at zero (ws is poisoned each call)
    hipMemsetAsync(ab, 0, BNE * sizeof(float), stream);

    build_weff_kernel<<<4096, 256, 0, stream>>>(Wq, Aq, Bq, weff + 0 * EE);
    build_weff_kernel<<<4096, 256, 0, stream>>>(Wk, Ak, Bk, weff + 1 * EE);
    build_weff_kernel<<<4096, 256, 0, stream>>>(Wv, Av, Bv, weff + 2 * EE);
    build_weff_kernel<<<4096, 256, 0, stream>>>(Wo, Ao, Bo, weff + 3 * EE);

    sort_kernel<<<BDIM, 256, 0, stream>>>(wbc, sidx + 0 * BDIM * NTOK);
    sort_kernel<<<BDIM, 256, 0, stream>>>(wbm, sidx + 1 * BDIM * NTOK);
    sort_kernel<<<BDIM, 256, 0, stream>>>(wbf, sidx + 2 * BDIM * NTOK);

    dim3 gg(EDIM / 128, MROWS / 128);   // (8, 64)
    gemm_nt_kernel<<<gg, 256, 0, stream>>>(x, weff + 0 * EE, bq, qb);
    gemm_nt_kernel<<<gg, 256, 0, stream>>>(x, weff + 1 * EE, bk, kb);
    gemm_nt_kernel<<<gg, 256, 0, stream>>>(x, weff + 2 * EE, bv, vb);

    dim3 ga(NTOK / 256, BDIM * HEADS);  // (16, 32)
    attn_kernel<256><<<ga, 256, 0, stream>>>(qb, kb, vb, sidx + 0 * BDIM * NTOK, ab);
    attn_kernel<64><<<ga, 256, 0, stream>>>(qb, kb, vb, sidx + 1 * BDIM * NTOK, ab);
    attn_kernel<16><<<ga, 256, 0, stream>>>(qb, kb, vb, sidx + 2 * BDIM * NTOK, ab);

    gemm_nt_kernel<<<gg, 256, 0, stream>>>(ab, weff + 3 * EE, bo, (float*)d_out);
}

// Round 2
// 1831.722 us; speedup vs baseline: 1.2968x; 1.2968x over previous
//
#include <hip/hip_runtime.h>
#include <cstdint>
#include <cstddef>

// Problem constants
#define BDIM 2
#define NTOK 4096
#define EDIM 1024
#define HEADS 16
#define HDIM 64
#define MROWS (BDIM * NTOK)   // 8192

typedef unsigned short u16;
typedef __attribute__((ext_vector_type(8))) short bf16x8;   // 8 bf16 = 4 VGPR
typedef __attribute__((ext_vector_type(4))) float f32x4;

// round-to-nearest-even split of fp32 into hi/lo bf16
__device__ inline void split2(float x, u16& h, u16& l) {
    union { float f; unsigned u; } a;
    a.f = x;
    unsigned uh = a.u + 0x7fff + ((a.u >> 16) & 1);
    h = (u16)(uh >> 16);
    union { unsigned u; float f; } hf; hf.u = (unsigned)h << 16;
    a.f = x - hf.f;
    unsigned ul = a.u + 0x7fff + ((a.u >> 16) & 1);
    l = (u16)(ul >> 16);
}

// global -> LDS direct 16B staging (lane i lands at lptr + i*16)
#define GLL(gp, lp) __builtin_amdgcn_global_load_lds( \
    (const __attribute__((address_space(1))) unsigned*)(gp), \
    (__attribute__((address_space(3))) unsigned*)(lp), 16, 0, 0)

// ---------------------------------------------------------------------------
// W_eff = W + 2*B@A, emitted directly as hi/lo bf16 pair
// ---------------------------------------------------------------------------
__global__ __launch_bounds__(256) void build_weff_kernel(
    const float* __restrict__ W, const float* __restrict__ A,
    const float* __restrict__ Bm, u16* __restrict__ dh, u16* __restrict__ dl)
{
    int idx = blockIdx.x * 256 + threadIdx.x;      // over E*E
    int o = idx >> 10, i = idx & 1023;
    float s = 0.f;
#pragma unroll
    for (int r = 0; r < 8; ++r) s += Bm[o * 8 + r] * A[r * 1024 + i];
    float w = W[idx] + 2.0f * s;
    u16 h, l;
    split2(w, h, l);
    dh[idx] = h; dl[idx] = l;
}

// ---------------------------------------------------------------------------
// fp32 buffer -> hi/lo bf16 buffers, 4 elements / thread
// ---------------------------------------------------------------------------
__global__ __launch_bounds__(256) void split_kernel(
    const float* __restrict__ src, u16* __restrict__ dh, u16* __restrict__ dl)
{
    int idx = blockIdx.x * 256 + threadIdx.x;      // one float4
    float4 v = ((const float4*)src)[idx];
    ushort4 h, l;
    split2(v.x, h.x, l.x);
    split2(v.y, h.y, l.y);
    split2(v.z, h.z, l.z);
    split2(v.w, h.w, l.w);
    ((ushort4*)dh)[idx] = h;
    ((ushort4*)dl)[idx] = l;
}

// ---------------------------------------------------------------------------
// Stable counting sort of one batch row of bucket ids (values < 256).
// ---------------------------------------------------------------------------
__global__ __launch_bounds__(256) void sort_kernel(
    const int* __restrict__ wb, int* __restrict__ sidx)
{
    __shared__ int sb[NTOK];
    __shared__ int hist[256];
    __shared__ int base[256];
    int t = threadIdx.x;
    int b = blockIdx.x;
    const int* w = wb + b * NTOK;
    for (int i = t; i < NTOK; i += 256) sb[i] = w[i];
    hist[t] = 0;
    __syncthreads();
    for (int i = t; i < NTOK; i += 256) atomicAdd(&hist[sb[i]], 1);
    __syncthreads();
    if (t == 0) {
        int run = 0;
        for (int u = 0; u < 256; ++u) { base[u] = run; run += hist[u]; }
    }
    __syncthreads();
    int pos = base[t];
    int* outp = sidx + b * NTOK;
    for (int n = 0; n < NTOK; ++n) {
        if (sb[n] == t) { outp[pos++] = n; }
    }
}

// ---------------------------------------------------------------------------
// Split-bf16 MFMA GEMM (NT): Y[m][n] = sum_k X[m][k]*W[n][k] + bias[n]
// X ~ Xh+Xl, W ~ Wh+Wl (bf16); Y = Xh*Wh + Xh*Wl + Xl*Wh (fp32 acc).
// 128x128 tile, BK=32, 4 waves in 2x2, each wave 64x64 via 4x4 16x16x32 MFMAs.
// LDS staged in MFMA-fragment order via global_load_lds (16B/lane).
// grid = (EDIM/128, M/128)
// ---------------------------------------------------------------------------
__global__ __launch_bounds__(256) void gemm_mfma_kernel(
    const u16* __restrict__ Xh, const u16* __restrict__ Xl,
    const u16* __restrict__ Wh, const u16* __restrict__ Wl,
    const float* __restrict__ bias, float* __restrict__ Y)
{
    __shared__ u16 lds[4 * 4096];          // Ah | Al | Bh | Bl, 8KB each
    u16* ldsAh = lds;
    u16* ldsAl = lds + 4096;
    u16* ldsBh = lds + 8192;
    u16* ldsBl = lds + 12288;
    int t = threadIdx.x;
    int lane = t & 63, wave = t >> 6;
    int m0 = blockIdx.y * 128, n0 = blockIdx.x * 128;
    int wm = (wave & 1) * 64, wn = (wave >> 1) * 64;
    f32x4 acc[4][4] = {};

    for (int kt = 0; kt < EDIM; kt += 32) {
        __syncthreads();                   // previous compute done
#pragma unroll
        for (int it = 0; it < 2; ++it) {
            int g = wave * 128 + it * 64 + lane;        // chunk id 0..511
            int row = ((g >> 6) << 4) | (g & 15);       // s*16 + m
            int kcol = kt + ((g >> 4) & 3) * 8;         // khalf*8
            int lo = (wave * 128 + it * 64) * 8;        // u16 offset (wave-uniform)
            GLL(Xh + (size_t)(m0 + row) * EDIM + kcol, ldsAh + lo);
            GLL(Xl + (size_t)(m0 + row) * EDIM + kcol, ldsAl + lo);
            GLL(Wh + (size_t)(n0 + row) * EDIM + kcol, ldsBh + lo);
            GLL(Wl + (size_t)(n0 + row) * EDIM + kcol, ldsBl + lo);
        }
        __syncthreads();                   // drains vmcnt before barrier

        int sA = wm >> 4, sB = wn >> 4;    // subtile bases (16-row units)
        bf16x8 ah[4], al[4], bh[4], bl[4];
#pragma unroll
        for (int i = 0; i < 4; ++i) {
            ah[i] = *(const bf16x8*)(ldsAh + ((sA + i) * 64 + lane) * 8);
            al[i] = *(const bf16x8*)(ldsAl + ((sA + i) * 64 + lane) * 8);
            bh[i] = *(const bf16x8*)(ldsBh + ((sB + i) * 64 + lane) * 8);
            bl[i] = *(const bf16x8*)(ldsBl + ((sB + i) * 64 + lane) * 8);
        }
#pragma unroll
        for (int i = 0; i < 4; ++i)
#pragma unroll
            for (int j = 0; j < 4; ++j) {
                acc[i][j] = __builtin_amdgcn_mfma_f32_16x16x32_bf16(ah[i], bh[j], acc[i][j], 0, 0, 0);
                acc[i][j] = __builtin_amdgcn_mfma_f32_16x16x32_bf16(ah[i], bl[j], acc[i][j], 0, 0, 0);
                acc[i][j] = __builtin_amdgcn_mfma_f32_16x16x32_bf16(al[i], bh[j], acc[i][j], 0, 0, 0);
            }
    }

    // epilogue: C/D layout col=lane&15, row=(lane>>4)*4+reg
    int col_in = lane & 15, rquad = lane >> 4;
#pragma unroll
    for (int j = 0; j < 4; ++j) {
        int col = n0 + wn + j * 16 + col_in;
        float bv = bias[col];
#pragma unroll
        for (int i = 0; i < 4; ++i) {
            int mbase = m0 + wm + i * 16 + rquad * 4;
#pragma unroll
            for (int r = 0; r < 4; ++r)
                Y[(size_t)(mbase + r) * EDIM + col] = acc[i][j][r] + bv;
        }
    }
}

// ---------------------------------------------------------------------------
// Chunked attention for one scale (chunk size C), fp32, online softmax.
// ---------------------------------------------------------------------------
template <int C>
__global__ __launch_bounds__(256) void attn_kernel(
    const float* __restrict__ Q, const float* __restrict__ K,
    const float* __restrict__ V, const int* __restrict__ sidx,
    float* __restrict__ out)
{
    __shared__ float sK[64][64];
    __shared__ float sV[64][64];
    int t = threadIdx.x;
    int bh = blockIdx.y;
    int b = bh >> 4, h = bh & 15;
    const int* sx = sidx + b * NTOK;
    int p0 = blockIdx.x * 256;
    int p = p0 + t;
    int c = p / C;
    int wstart = (c == 0) ? 0 : (c - 1) * C;
    int wend = (c + 1) * C;
    int c0 = p0 / C;
    int c1 = (p0 + 255) / C;
    int kmin = (c0 > 0) ? (c0 - 1) * C : 0;
    int kmax = (c1 + 1) * C;

    int r = sx[p];
    const float* qrow = Q + (size_t)(b * NTOK + r) * EDIM + h * HDIM;
    float4 q4[16], acc[16];
#pragma unroll
    for (int i = 0; i < 16; ++i) {
        q4[i] = ((const float4*)qrow)[i];
        acc[i] = make_float4(0.f, 0.f, 0.f, 0.f);
    }
    float m = -1e30f, l = 0.f;

    for (int ks = kmin; ks < kmax; ks += 64) {
        int nk = min(64, kmax - ks);
        __syncthreads();
        for (int idx = t; idx < nk * 16; idx += 256) {
            int j = idx >> 4, d4 = idx & 15;
            int tok = sx[ks + j];
            size_t rowo = (size_t)(b * NTOK + tok) * EDIM + h * HDIM;
            ((float4*)sK[j])[d4] = ((const float4*)(K + rowo))[d4];
            ((float4*)sV[j])[d4] = ((const float4*)(V + rowo))[d4];
        }
        __syncthreads();
        int jlo = max(ks, wstart) - ks;
        int jhi = min(ks + nk, wend) - ks;
        for (int g = jlo; g < jhi; g += 16) {
            float s[16];
            float mu = -1e30f;
#pragma unroll
            for (int jj = 0; jj < 16; ++jj) {
                float sum = 0.f;
                const float4* kr = (const float4*)sK[g + jj];
#pragma unroll
                for (int i = 0; i < 16; ++i) {
                    float4 kv = kr[i];
                    sum += q4[i].x * kv.x + q4[i].y * kv.y +
                           q4[i].z * kv.z + q4[i].w * kv.w;
                }
                s[jj] = sum * 0.125f;
                mu = fmaxf(mu, s[jj]);
            }
            if (mu > m) {
                float alpha = __expf(m - mu);
                l *= alpha;
#pragma unroll
                for (int i = 0; i < 16; ++i) {
                    acc[i].x *= alpha; acc[i].y *= alpha;
                    acc[i].z *= alpha; acc[i].w *= alpha;
                }
                m = mu;
            }
#pragma unroll
            for (int jj = 0; jj < 16; ++jj) {
                float pw = __expf(s[jj] - m);
                l += pw;
                const float4* vr = (const float4*)sV[g + jj];
#pragma unroll
                for (int i = 0; i < 16; ++i) {
                    float4 vv = vr[i];
                    acc[i].x += pw * vv.x; acc[i].y += pw * vv.y;
                    acc[i].z += pw * vv.z; acc[i].w += pw * vv.w;
                }
            }
        }
    }
    float inv = 1.0f / (3.0f * l);
    float* orow = out + (size_t)(b * NTOK + r) * EDIM + h * HDIM;
#pragma unroll
    for (int i = 0; i < 16; ++i) {
        float4 o = ((float4*)orow)[i];
        o.x += acc[i].x * inv; o.y += acc[i].y * inv;
        o.z += acc[i].z * inv; o.w += acc[i].w * inv;
        ((float4*)orow)[i] = o;
    }
}

// ---------------------------------------------------------------------------
extern "C" void kernel_launch(void* const* d_in, const int* in_sizes, int n_in,
                              void* d_out, int out_size, void* d_ws, size_t ws_size,
                              hipStream_t stream)
{
    const float* x   = (const float*)d_in[0];
    const int*   wbc = (const int*)d_in[1];
    const int*   wbm = (const int*)d_in[2];
    const int*   wbf = (const int*)d_in[3];
    const float* Wq = (const float*)d_in[4],  *bq = (const float*)d_in[5];
    const float* Aq = (const float*)d_in[6],  *Bq = (const float*)d_in[7];
    const float* Wk = (const float*)d_in[8],  *bk = (const float*)d_in[9];
    const float* Ak = (const float*)d_in[10], *Bk = (const float*)d_in[11];
    const float* Wv = (const float*)d_in[12], *bv = (const float*)d_in[13];
    const float* Av = (const float*)d_in[14], *Bv = (const float*)d_in[15];
    const float* Wo = (const float*)d_in[16], *bo = (const float*)d_in[17];
    const float* Ao = (const float*)d_in[18], *Bo = (const float*)d_in[19];

    const size_t EE  = (size_t)EDIM * EDIM;        // 1,048,576
    const size_t BNE = (size_t)MROWS * EDIM;       // 8,388,608

    char* wsb = (char*)d_ws;
    float* qb = (float*)wsb;                        wsb += BNE * 4;
    float* kb = (float*)wsb;                        wsb += BNE * 4;
    float* vb = (float*)wsb;                        wsb += BNE * 4;
    float* ab = (float*)wsb;                        wsb += BNE * 4;
    u16* xh = (u16*)wsb;                            wsb += BNE * 2;   // also abh
    u16* xl = (u16*)wsb;                            wsb += BNE * 2;   // also abl
    u16* wsp = (u16*)wsb;                           wsb += 8 * EE * 2;
    int* sidx = (int*)wsb;                          wsb += 3 * BDIM * NTOK * 4;

    u16* wqh = wsp + 0 * EE, *wql = wsp + 1 * EE;
    u16* wkh = wsp + 2 * EE, *wkl = wsp + 3 * EE;
    u16* wvh = wsp + 4 * EE, *wvl = wsp + 5 * EE;
    u16* woh = wsp + 6 * EE, *wol = wsp + 7 * EE;

    // attention accumulator must start at zero (ws is poisoned each call)
    hipMemsetAsync(ab, 0, BNE * sizeof(float), stream);

    split_kernel<<<BNE / 1024, 256, 0, stream>>>(x, xh, xl);

    build_weff_kernel<<<4096, 256, 0, stream>>>(Wq, Aq, Bq, wqh, wql);
    build_weff_kernel<<<4096, 256, 0, stream>>>(Wk, Ak, Bk, wkh, wkl);
    build_weff_kernel<<<4096, 256, 0, stream>>>(Wv, Av, Bv, wvh, wvl);
    build_weff_kernel<<<4096, 256, 0, stream>>>(Wo, Ao, Bo, woh, wol);

    sort_kernel<<<BDIM, 256, 0, stream>>>(wbc, sidx + 0 * BDIM * NTOK);
    sort_kernel<<<BDIM, 256, 0, stream>>>(wbm, sidx + 1 * BDIM * NTOK);
    sort_kernel<<<BDIM, 256, 0, stream>>>(wbf, sidx + 2 * BDIM * NTOK);

    dim3 gg(EDIM / 128, MROWS / 128);   // (8, 64)
    gemm_mfma_kernel<<<gg, 256, 0, stream>>>(xh, xl, wqh, wql, bq, qb);
    gemm_mfma_kernel<<<gg, 256, 0, stream>>>(xh, xl, wkh, wkl, bk, kb);
    gemm_mfma_kernel<<<gg, 256, 0, stream>>>(xh, xl, wvh, wvl, bv, vb);

    dim3 ga(NTOK / 256, BDIM * HEADS);  // (16, 32)
    attn_kernel<256><<<ga, 256, 0, stream>>>(qb, kb, vb, sidx + 0 * BDIM * NTOK, ab);
    attn_kernel<64><<<ga, 256, 0, stream>>>(qb, kb, vb, sidx + 1 * BDIM * NTOK, ab);
    attn_kernel<16><<<ga, 256, 0, stream>>>(qb, kb, vb, sidx + 2 * BDIM * NTOK, ab);

    // reuse xh/xl space for the attention-output split
    split_kernel<<<BNE / 1024, 256, 0, stream>>>(ab, xh, xl);
    gemm_mfma_kernel<<<gg, 256, 0, stream>>>(xh, xl, woh, wol, bo, (float*)d_out);
}

// Round 3
// 905.580 us; speedup vs baseline: 2.6231x; 2.0227x over previous
//
#include <hip/hip_runtime.h>
#include <cstdint>
#include <cstddef>

// Problem constants
#define BDIM 2
#define NTOK 4096
#define EDIM 1024
#define HEADS 16
#define HDIM 64
#define MROWS (BDIM * NTOK)   // 8192

typedef unsigned short u16;
typedef __attribute__((ext_vector_type(8))) short bf16x8;   // 8 bf16 = 4 VGPR
typedef __attribute__((ext_vector_type(4))) float f32x4;

#define MFMA(a, b, c) __builtin_amdgcn_mfma_f32_16x16x32_bf16(a, b, c, 0, 0, 0)

// round-to-nearest-even split of fp32 into hi/lo bf16
__device__ inline void split2(float x, u16& h, u16& l) {
    union { float f; unsigned u; } a;
    a.f = x;
    unsigned uh = a.u + 0x7fff + ((a.u >> 16) & 1);
    h = (u16)(uh >> 16);
    union { unsigned u; float f; } hf; hf.u = (unsigned)h << 16;
    a.f = x - hf.f;
    unsigned ul = a.u + 0x7fff + ((a.u >> 16) & 1);
    l = (u16)(ul >> 16);
}

__device__ inline u16 bf16rne(float x) {
    union { float f; unsigned u; } a; a.f = x;
    unsigned r = a.u + 0x7fff + ((a.u >> 16) & 1);
    return (u16)(r >> 16);
}

// global -> LDS direct 16B staging (lane i lands at lptr + i*16)
#define GLL(gp, lp) __builtin_amdgcn_global_load_lds( \
    (const __attribute__((address_space(1))) unsigned*)(gp), \
    (__attribute__((address_space(3))) unsigned*)(lp), 16, 0, 0)

// ---------------------------------------------------------------------------
// W_eff = W + 2*B@A, emitted directly as hi/lo bf16 pair
// ---------------------------------------------------------------------------
__global__ __launch_bounds__(256) void build_weff_kernel(
    const float* __restrict__ W, const float* __restrict__ A,
    const float* __restrict__ Bm, u16* __restrict__ dh, u16* __restrict__ dl)
{
    int idx = blockIdx.x * 256 + threadIdx.x;      // over E*E
    int o = idx >> 10, i = idx & 1023;
    float s = 0.f;
#pragma unroll
    for (int r = 0; r < 8; ++r) s += Bm[o * 8 + r] * A[r * 1024 + i];
    float w = W[idx] + 2.0f * s;
    u16 h, l;
    split2(w, h, l);
    dh[idx] = h; dl[idx] = l;
}

// ---------------------------------------------------------------------------
// fp32 buffer -> hi/lo bf16 buffers, 4 elements / thread
// ---------------------------------------------------------------------------
__global__ __launch_bounds__(256) void split_kernel(
    const float* __restrict__ src, u16* __restrict__ dh, u16* __restrict__ dl)
{
    int idx = blockIdx.x * 256 + threadIdx.x;      // one float4
    float4 v = ((const float4*)src)[idx];
    ushort4 h, l;
    split2(v.x, h.x, l.x);
    split2(v.y, h.y, l.y);
    split2(v.z, h.z, l.z);
    split2(v.w, h.w, l.w);
    ((ushort4*)dh)[idx] = h;
    ((ushort4*)dl)[idx] = l;
}

// ---------------------------------------------------------------------------
// Stable counting sort, 3 scales x BDIM batches in one launch. grid=(BDIM,3)
// ---------------------------------------------------------------------------
__global__ __launch_bounds__(256) void sort3_kernel(
    const int* __restrict__ w0, const int* __restrict__ w1,
    const int* __restrict__ w2, int* __restrict__ sidx)
{
    __shared__ int sb[NTOK];
    __shared__ int hist[256];
    __shared__ int base[256];
    const int* srcs[3] = {w0, w1, w2};
    int t = threadIdx.x;
    const int* w = srcs[blockIdx.y] + blockIdx.x * NTOK;
    int* outp = sidx + ((int)blockIdx.y * BDIM + (int)blockIdx.x) * NTOK;
    for (int i = t; i < NTOK; i += 256) sb[i] = w[i];
    hist[t] = 0;
    __syncthreads();
    for (int i = t; i < NTOK; i += 256) atomicAdd(&hist[sb[i]], 1);
    __syncthreads();
    if (t == 0) {
        int run = 0;
        for (int u = 0; u < 256; ++u) { base[u] = run; run += hist[u]; }
    }
    __syncthreads();
    int pos = base[t];
    for (int n = 0; n < NTOK; ++n) {
        if (sb[n] == t) { outp[pos++] = n; }
    }
}

// ---------------------------------------------------------------------------
// Split-bf16 MFMA GEMM (NT): Y[m][n] = sum_k X[m][k]*W[n][k] + bias[n]
// ---------------------------------------------------------------------------
__global__ __launch_bounds__(256) void gemm_mfma_kernel(
    const u16* __restrict__ Xh, const u16* __restrict__ Xl,
    const u16* __restrict__ Wh, const u16* __restrict__ Wl,
    const float* __restrict__ bias, float* __restrict__ Y)
{
    __shared__ u16 lds[4 * 4096];          // Ah | Al | Bh | Bl, 8KB each
    u16* ldsAh = lds;
    u16* ldsAl = lds + 4096;
    u16* ldsBh = lds + 8192;
    u16* ldsBl = lds + 12288;
    int t = threadIdx.x;
    int lane = t & 63, wave = t >> 6;
    int m0 = blockIdx.y * 128, n0 = blockIdx.x * 128;
    int wm = (wave & 1) * 64, wn = (wave >> 1) * 64;
    f32x4 acc[4][4] = {};

    for (int kt = 0; kt < EDIM; kt += 32) {
        __syncthreads();
#pragma unroll
        for (int it = 0; it < 2; ++it) {
            int g = wave * 128 + it * 64 + lane;        // chunk id 0..511
            int row = ((g >> 6) << 4) | (g & 15);       // s*16 + m
            int kcol = kt + ((g >> 4) & 3) * 8;         // khalf*8
            int lo = (wave * 128 + it * 64) * 8;        // u16 offset (wave-uniform)
            GLL(Xh + (size_t)(m0 + row) * EDIM + kcol, ldsAh + lo);
            GLL(Xl + (size_t)(m0 + row) * EDIM + kcol, ldsAl + lo);
            GLL(Wh + (size_t)(n0 + row) * EDIM + kcol, ldsBh + lo);
            GLL(Wl + (size_t)(n0 + row) * EDIM + kcol, ldsBl + lo);
        }
        __syncthreads();

        int sA = wm >> 4, sB = wn >> 4;
        bf16x8 ah[4], al[4], bh[4], bl[4];
#pragma unroll
        for (int i = 0; i < 4; ++i) {
            ah[i] = *(const bf16x8*)(ldsAh + ((sA + i) * 64 + lane) * 8);
            al[i] = *(const bf16x8*)(ldsAl + ((sA + i) * 64 + lane) * 8);
            bh[i] = *(const bf16x8*)(ldsBh + ((sB + i) * 64 + lane) * 8);
            bl[i] = *(const bf16x8*)(ldsBl + ((sB + i) * 64 + lane) * 8);
        }
#pragma unroll
        for (int i = 0; i < 4; ++i)
#pragma unroll
            for (int j = 0; j < 4; ++j) {
                acc[i][j] = MFMA(ah[i], bh[j], acc[i][j]);
                acc[i][j] = MFMA(ah[i], bl[j], acc[i][j]);
                acc[i][j] = MFMA(al[i], bh[j], acc[i][j]);
            }
    }

    int col_in = lane & 15, rquad = lane >> 4;
#pragma unroll
    for (int j = 0; j < 4; ++j) {
        int col = n0 + wn + j * 16 + col_in;
        float bv = bias[col];
#pragma unroll
        for (int i = 0; i < 4; ++i) {
            int mbase = m0 + wm + i * 16 + rquad * 4;
#pragma unroll
            for (int r = 0; r < 4; ++r)
                Y[(size_t)(mbase + r) * EDIM + col] = acc[i][j][r] + bv;
        }
    }
}

// ---------------------------------------------------------------------------
// MFMA flash attention for one scale (chunk C). Block = 128 sorted queries
// (4 waves x 2 16-query MFMA tiles), grid = (NTOK/128, B*H).
// K split hi/lo (3-pass QK^T), V hi (2-pass PV with P split hi/lo).
// Online softmax with quad-group shared max + deferred l reduction.
// out[token] += attn/(3*l)
// ---------------------------------------------------------------------------
template <int C>
__global__ __launch_bounds__(256, 3) void attn_mfma_kernel(
    const float* __restrict__ Q, const float* __restrict__ K,
    const float* __restrict__ V, const int* __restrict__ sidx,
    float* __restrict__ out)
{
    // K fragments: [s(4)][kk(2)][lane(64)][8]; V: [kk2(2)][dt(4)][lane(64)][8]
    __shared__ u16 KfH[4096], KfL[4096], VfH[4096];
    __shared__ u16 PbH[4 * 768], PbL[4 * 768];     // per-wave P relayout, row stride 48

    int t = threadIdx.x;
    int lane = t & 63, wave = t >> 6;
    int quad = lane >> 4, l16 = lane & 15;
    int bh = blockIdx.y, b = bh >> 4, h = bh & 15;
    int p0 = blockIdx.x * 128;
    const int* sxb = sidx + b * NTOK;

    // ---- per-tile setup: windows + Q fragments (scaled by 1/sqrt(64)) ----
    int ptile[2], ws_[2], we_[2];
    bf16x8 qh[2][2], ql[2][2];
#pragma unroll
    for (int tq = 0; tq < 2; ++tq) {
        ptile[tq] = p0 + wave * 32 + tq * 16;
        int c = ptile[tq] / C;
        ws_[tq] = (c > 0) ? (c - 1) * C : 0;
        we_[tq] = (c + 1) * C;
        int qrow = sxb[ptile[tq] + l16];
        const float* qp = Q + ((size_t)(b * NTOK + qrow)) * EDIM + h * HDIM;
#pragma unroll
        for (int kk = 0; kk < 2; ++kk) {
            float4 f0 = *(const float4*)(qp + kk * 32 + quad * 8);
            float4 f1 = *(const float4*)(qp + kk * 32 + quad * 8 + 4);
            float fa[8] = {f0.x, f0.y, f0.z, f0.w, f1.x, f1.y, f1.z, f1.w};
            bf16x8 hv, lv;
#pragma unroll
            for (int e = 0; e < 8; ++e) {
                u16 hh, ll;
                split2(fa[e] * 0.125f, hh, ll);
                hv[e] = (short)hh; lv[e] = (short)ll;
            }
            qh[tq][kk] = hv; ql[tq][kk] = lv;
        }
    }

    f32x4 oacc[2][4] = {};
    float lpart[2][4] = {};
    float mrun[2] = {-1e30f, -1e30f};

    int c0 = p0 / C, c1 = (p0 + 127) / C;
    int kmin = (c0 > 0) ? (c0 - 1) * C : 0;
    int kmax = (c1 + 1) * C;

    for (int ks = kmin; ks < kmax; ks += 64) {
        int nk = min(64, kmax - ks);
        __syncthreads();                     // previous slab fully consumed
        // ---- stage K (hi/lo) + V (hi) for 64 keys, fragment order ----
#pragma unroll
        for (int it = 0; it < 4; ++it) {
            int idx = it * 256 + t;          // 0..1023
            int key = idx >> 4, d4 = idx & 15;
            int d = d4 * 4;
            int vbase0 = ((key >> 5) * 2048) + (((key >> 3) & 3) * 128) + (key & 7);
            if (key < nk) {
                int tok = sxb[ks + key];
                size_t rowo = ((size_t)(b * NTOK + tok)) * EDIM + h * HDIM + d;
                float4 fk = *(const float4*)(K + rowo);
                float4 fv = *(const float4*)(V + rowo);
                int kk = d >> 5, qd = (d >> 3) & 3, j = d & 7;
                int kbase = (((key >> 4) * 2 + kk) * 64 + qd * 16 + (key & 15)) * 8 + j;
                ushort4 hh, ll;
                split2(fk.x, hh.x, ll.x); split2(fk.y, hh.y, ll.y);
                split2(fk.z, hh.z, ll.z); split2(fk.w, hh.w, ll.w);
                *(ushort4*)(KfH + kbase) = hh;
                *(ushort4*)(KfL + kbase) = ll;
                float fva[4] = {fv.x, fv.y, fv.z, fv.w};
#pragma unroll
                for (int e = 0; e < 4; ++e) {
                    int dim = d + e;
                    VfH[vbase0 + (dim >> 4) * 512 + (dim & 15) * 8] = bf16rne(fva[e]);
                }
            } else {
                // zero-fill V so masked keys can't inject NaN via P=0 * garbage
#pragma unroll
                for (int e = 0; e < 4; ++e) {
                    int dim = d + e;
                    VfH[vbase0 + (dim >> 4) * 512 + (dim & 15) * 8] = 0;
                }
            }
        }
        __syncthreads();

        // ---- per-wave windows within this slab ----
        int jlo0 = max(ks, ws_[0]) - ks, jhi0 = min(ks + nk, we_[0]) - ks;
        int jlo1 = max(ks, ws_[1]) - ks, jhi1 = min(ks + nk, we_[1]) - ks;
        bool e0 = jlo0 < jhi0, e1 = jlo1 < jhi1;
        if (!e0 && !e1) continue;            // barriers stay in lockstep
        int glo = e0 ? (e1 ? min(jlo0, jlo1) : jlo0) : jlo1;
        int ghi = e0 ? (e1 ? max(jhi0, jhi1) : jhi0) : jhi1;

        for (int g0 = glo & ~31; g0 < ghi; g0 += 32) {
            int s0i = g0 >> 4;
            int s1i = min(s0i + 1, 3);
            bf16x8 kh0[2], kl0[2], kh1[2], kl1[2];
#pragma unroll
            for (int kk = 0; kk < 2; ++kk) {
                kh0[kk] = *(const bf16x8*)(KfH + ((s0i * 2 + kk) * 64 + lane) * 8);
                kl0[kk] = *(const bf16x8*)(KfL + ((s0i * 2 + kk) * 64 + lane) * 8);
                kh1[kk] = *(const bf16x8*)(KfH + ((s1i * 2 + kk) * 64 + lane) * 8);
                kl1[kk] = *(const bf16x8*)(KfL + ((s1i * 2 + kk) * 64 + lane) * 8);
            }
#pragma unroll
            for (int tq = 0; tq < 2; ++tq) {
                int jl = tq ? jlo1 : jlo0, jh = tq ? jhi1 : jhi0;
                bool v0 = (g0 >= jl) && (g0 < jh);
                bool v1 = (g0 + 16 >= jl) && (g0 + 16 < jh);
                if (!v0 && !v1) continue;
                f32x4 sa = {0.f, 0.f, 0.f, 0.f}, sb = {0.f, 0.f, 0.f, 0.f};
                if (v0) {
                    sa = MFMA(qh[tq][0], kh0[0], sa);
                    sa = MFMA(qh[tq][0], kl0[0], sa);
                    sa = MFMA(ql[tq][0], kh0[0], sa);
                    sa = MFMA(qh[tq][1], kh0[1], sa);
                    sa = MFMA(qh[tq][1], kl0[1], sa);
                    sa = MFMA(ql[tq][1], kh0[1], sa);
                }
                if (v1) {
                    sb = MFMA(qh[tq][0], kh1[0], sb);
                    sb = MFMA(qh[tq][0], kl1[0], sb);
                    sb = MFMA(ql[tq][0], kh1[0], sb);
                    sb = MFMA(qh[tq][1], kh1[1], sb);
                    sb = MFMA(qh[tq][1], kl1[1], sb);
                    sb = MFMA(ql[tq][1], kh1[1], sb);
                }
                // quad-group shared max (valid upper bound for all 4 rows)
                float smax = -1e30f;
                if (v0) smax = fmaxf(smax, fmaxf(fmaxf(sa[0], sa[1]), fmaxf(sa[2], sa[3])));
                if (v1) smax = fmaxf(smax, fmaxf(fmaxf(sb[0], sb[1]), fmaxf(sb[2], sb[3])));
                smax = fmaxf(smax, __shfl_xor(smax, 1));
                smax = fmaxf(smax, __shfl_xor(smax, 2));
                smax = fmaxf(smax, __shfl_xor(smax, 4));
                smax = fmaxf(smax, __shfl_xor(smax, 8));
                float mold = mrun[tq];
                float mnew = fmaxf(mold, smax);
                mrun[tq] = mnew;
                float alpha = __expf(mold - mnew);
#pragma unroll
                for (int r = 0; r < 4; ++r) lpart[tq][r] *= alpha;
#pragma unroll
                for (int dt = 0; dt < 4; ++dt) {
                    oacc[tq][dt][0] *= alpha; oacc[tq][dt][1] *= alpha;
                    oacc[tq][dt][2] *= alpha; oacc[tq][dt][3] *= alpha;
                }
                u16* pbh = PbH + wave * 768;
                u16* pbl = PbL + wave * 768;
#pragma unroll
                for (int r = 0; r < 4; ++r) {
                    float pa = v0 ? __expf(sa[r] - mnew) : 0.f;
                    float pb = v1 ? __expf(sb[r] - mnew) : 0.f;
                    lpart[tq][r] += pa + pb;
                    u16 hh, ll;
                    split2(pa, hh, ll);
                    pbh[(quad * 4 + r) * 48 + l16] = hh;
                    pbl[(quad * 4 + r) * 48 + l16] = ll;
                    split2(pb, hh, ll);
                    pbh[(quad * 4 + r) * 48 + 16 + l16] = hh;
                    pbl[(quad * 4 + r) * 48 + 16 + l16] = ll;
                }
                bf16x8 ph = *(const bf16x8*)(pbh + l16 * 48 + quad * 8);
                bf16x8 pl = *(const bf16x8*)(pbl + l16 * 48 + quad * 8);
                int vbase = (g0 >> 5) * 2048;
#pragma unroll
                for (int dt = 0; dt < 4; ++dt) {
                    bf16x8 vv = *(const bf16x8*)(VfH + vbase + dt * 512 + lane * 8);
                    oacc[tq][dt] = MFMA(ph, vv, oacc[tq][dt]);
                    oacc[tq][dt] = MFMA(pl, vv, oacc[tq][dt]);
                }
            }
        }
    }

    // ---- epilogue: reduce l across the 16 key-lanes, scale, accumulate ----
#pragma unroll
    for (int tq = 0; tq < 2; ++tq) {
        float inv[4];
#pragma unroll
        for (int r = 0; r < 4; ++r) {
            float v = lpart[tq][r];
            v += __shfl_xor(v, 1);
            v += __shfl_xor(v, 2);
            v += __shfl_xor(v, 4);
            v += __shfl_xor(v, 8);
            inv[r] = 1.0f / (3.0f * v);
        }
#pragma unroll
        for (int r = 0; r < 4; ++r) {
            int tok = sxb[ptile[tq] + quad * 4 + r];
            float* op = out + ((size_t)(b * NTOK + tok)) * EDIM + h * HDIM + l16;
#pragma unroll
            for (int dt = 0; dt < 4; ++dt)
                op[dt * 16] += oacc[tq][dt][r] * inv[r];
        }
    }
}

// ---------------------------------------------------------------------------
extern "C" void kernel_launch(void* const* d_in, const int* in_sizes, int n_in,
                              void* d_out, int out_size, void* d_ws, size_t ws_size,
                              hipStream_t stream)
{
    const float* x   = (const float*)d_in[0];
    const int*   wbc = (const int*)d_in[1];
    const int*   wbm = (const int*)d_in[2];
    const int*   wbf = (const int*)d_in[3];
    const float* Wq = (const float*)d_in[4],  *bq = (const float*)d_in[5];
    const float* Aq = (const float*)d_in[6],  *Bq = (const float*)d_in[7];
    const float* Wk = (const float*)d_in[8],  *bk = (const float*)d_in[9];
    const float* Ak = (const float*)d_in[10], *Bk = (const float*)d_in[11];
    const float* Wv = (const float*)d_in[12], *bv = (const float*)d_in[13];
    const float* Av = (const float*)d_in[14], *Bv = (const float*)d_in[15];
    const float* Wo = (const float*)d_in[16], *bo = (const float*)d_in[17];
    const float* Ao = (const float*)d_in[18], *Bo = (const float*)d_in[19];

    const size_t EE  = (size_t)EDIM * EDIM;        // 1,048,576
    const size_t BNE = (size_t)MROWS * EDIM;       // 8,388,608

    char* wsb = (char*)d_ws;
    float* qb = (float*)wsb;                        wsb += BNE * 4;
    float* kb = (float*)wsb;                        wsb += BNE * 4;
    float* vb = (float*)wsb;                        wsb += BNE * 4;
    float* ab = (float*)wsb;                        wsb += BNE * 4;
    u16* xh = (u16*)wsb;                            wsb += BNE * 2;   // also abh
    u16* xl = (u16*)wsb;                            wsb += BNE * 2;   // also abl
    u16* wsp = (u16*)wsb;                           wsb += 8 * EE * 2;
    int* sidx = (int*)wsb;                          wsb += 3 * BDIM * NTOK * 4;

    u16* wqh = wsp + 0 * EE, *wql = wsp + 1 * EE;
    u16* wkh = wsp + 2 * EE, *wkl = wsp + 3 * EE;
    u16* wvh = wsp + 4 * EE, *wvl = wsp + 5 * EE;
    u16* woh = wsp + 6 * EE, *wol = wsp + 7 * EE;

    // attention accumulator must start at zero (ws is poisoned each call)
    hipMemsetAsync(ab, 0, BNE * sizeof(float), stream);

    split_kernel<<<BNE / 1024, 256, 0, stream>>>(x, xh, xl);

    build_weff_kernel<<<4096, 256, 0, stream>>>(Wq, Aq, Bq, wqh, wql);
    build_weff_kernel<<<4096, 256, 0, stream>>>(Wk, Ak, Bk, wkh, wkl);
    build_weff_kernel<<<4096, 256, 0, stream>>>(Wv, Av, Bv, wvh, wvl);
    build_weff_kernel<<<4096, 256, 0, stream>>>(Wo, Ao, Bo, woh, wol);

    sort3_kernel<<<dim3(BDIM, 3), 256, 0, stream>>>(wbc, wbm, wbf, sidx);

    dim3 gg(EDIM / 128, MROWS / 128);   // (8, 64)
    gemm_mfma_kernel<<<gg, 256, 0, stream>>>(xh, xl, wqh, wql, bq, qb);
    gemm_mfma_kernel<<<gg, 256, 0, stream>>>(xh, xl, wkh, wkl, bk, kb);
    gemm_mfma_kernel<<<gg, 256, 0, stream>>>(xh, xl, wvh, wvl, bv, vb);

    dim3 ga(NTOK / 128, BDIM * HEADS);  // (32, 32)
    attn_mfma_kernel<256><<<ga, 256, 0, stream>>>(qb, kb, vb, sidx + 0 * BDIM * NTOK, ab);
    attn_mfma_kernel<64><<<ga, 256, 0, stream>>>(qb, kb, vb, sidx + 1 * BDIM * NTOK, ab);
    attn_mfma_kernel<16><<<ga, 256, 0, stream>>>(qb, kb, vb, sidx + 2 * BDIM * NTOK, ab);

    // reuse xh/xl space for the attention-output split
    split_kernel<<<BNE / 1024, 256, 0, stream>>>(ab, xh, xl);
    gemm_mfma_kernel<<<gg, 256, 0, stream>>>(xh, xl, woh, wol, bo, (float*)d_out);
}

// Round 4
// 675.515 us; speedup vs baseline: 3.5165x; 1.3406x over previous
//
#include <hip/hip_runtime.h>
#include <cstdint>
#include <cstddef>

// Problem constants
#define BDIM 2
#define NTOK 4096
#define EDIM 1024
#define HEADS 16
#define HDIM 64
#define MROWS (BDIM * NTOK)   // 8192

typedef unsigned short u16;
typedef __attribute__((ext_vector_type(8))) short bf16x8;   // 8 bf16 = 4 VGPR
typedef __attribute__((ext_vector_type(4))) float f32x4;

#define MFMA(a, b, c) __builtin_amdgcn_mfma_f32_16x16x32_bf16(a, b, c, 0, 0, 0)

// round-to-nearest-even split of fp32 into hi/lo bf16
__device__ inline void split2(float x, u16& h, u16& l) {
    union { float f; unsigned u; } a;
    a.f = x;
    unsigned uh = a.u + 0x7fff + ((a.u >> 16) & 1);
    h = (u16)(uh >> 16);
    union { unsigned u; float f; } hf; hf.u = (unsigned)h << 16;
    a.f = x - hf.f;
    unsigned ul = a.u + 0x7fff + ((a.u >> 16) & 1);
    l = (u16)(ul >> 16);
}

__device__ inline u16 bf16rne(float x) {
    union { float f; unsigned u; } a; a.f = x;
    unsigned r = a.u + 0x7fff + ((a.u >> 16) & 1);
    return (u16)(r >> 16);
}

// global -> LDS direct 16B staging (lane i lands at lptr + i*16)
#define GLL(gp, lp) __builtin_amdgcn_global_load_lds( \
    (const __attribute__((address_space(1))) unsigned*)(gp), \
    (__attribute__((address_space(3))) unsigned*)(lp), 16, 0, 0)

// ---------------------------------------------------------------------------
// W_eff = W + 2*B@A, emitted directly as hi/lo bf16 pair
// ---------------------------------------------------------------------------
__global__ __launch_bounds__(256) void build_weff_kernel(
    const float* __restrict__ W, const float* __restrict__ A,
    const float* __restrict__ Bm, u16* __restrict__ dh, u16* __restrict__ dl)
{
    int idx = blockIdx.x * 256 + threadIdx.x;      // over E*E
    int o = idx >> 10, i = idx & 1023;
    float s = 0.f;
#pragma unroll
    for (int r = 0; r < 8; ++r) s += Bm[o * 8 + r] * A[r * 1024 + i];
    float w = W[idx] + 2.0f * s;
    u16 h, l;
    split2(w, h, l);
    dh[idx] = h; dl[idx] = l;
}

// ---------------------------------------------------------------------------
// fp32 buffer -> hi/lo bf16 buffers, 4 elements / thread
// ---------------------------------------------------------------------------
__global__ __launch_bounds__(256) void split_kernel(
    const float* __restrict__ src, u16* __restrict__ dh, u16* __restrict__ dl)
{
    int idx = blockIdx.x * 256 + threadIdx.x;      // one float4
    float4 v = ((const float4*)src)[idx];
    ushort4 h, l;
    split2(v.x, h.x, l.x);
    split2(v.y, h.y, l.y);
    split2(v.z, h.z, l.z);
    split2(v.w, h.w, l.w);
    ((ushort4*)dh)[idx] = h;
    ((ushort4*)dl)[idx] = l;
}

// ---------------------------------------------------------------------------
// Parallel stable counting sort, 3 scales x BDIM batches. grid=(BDIM,3).
// 32 groups x 128 elements: group histograms -> per-bucket prefix across
// groups -> global bucket scan -> 32-way parallel stable placement.
// Critical path ~128 LDS iters (was 4096 serial).
// ---------------------------------------------------------------------------
__global__ __launch_bounds__(256) void sort3_kernel(
    const int* __restrict__ w0, const int* __restrict__ w1,
    const int* __restrict__ w2, int* __restrict__ sidx)
{
    __shared__ int sb[NTOK];          // 16 KB
    __shared__ int cnt[32][256];      // 32 KB
    __shared__ int gb[256];           // 1 KB
    const int* srcs[3] = {w0, w1, w2};
    int t = threadIdx.x;
    const int* w = srcs[blockIdx.y] + blockIdx.x * NTOK;
    int* outp = sidx + ((int)blockIdx.y * BDIM + (int)blockIdx.x) * NTOK;

    for (int i = t; i < NTOK; i += 256) sb[i] = w[i];
    for (int i = t; i < 32 * 256; i += 256) ((int*)cnt)[i] = 0;
    __syncthreads();

    // phase 1: per-group histogram (order-free). group = t>>3, 8 threads each,
    // elements strided by 8 within the group to spread LDS banks.
    int g = t >> 3;
#pragma unroll
    for (int e = 0; e < 16; ++e)
        atomicAdd(&cnt[g][sb[g * 128 + (t & 7) + 8 * e]], 1);
    __syncthreads();

    // phase 2: per-bucket (thread = bucket) exclusive prefix across groups
    int run = 0;
#pragma unroll
    for (int gg = 0; gg < 32; ++gg) {
        int c = cnt[gg][t];
        cnt[gg][t] = run;
        run += c;
    }
    gb[t] = run;                      // bucket totals
    __syncthreads();
    if (t == 0) {                     // global bucket bases (256 serial, ~1us)
        int acc = 0;
        for (int v = 0; v < 256; ++v) { int c = gb[v]; gb[v] = acc; acc += c; }
    }
    __syncthreads();
    for (int i = t; i < 32 * 256; i += 256) {
        int v = i & 255, gg = i >> 8;
        cnt[gg][v] += gb[v];          // cnt[g][v] = final start offset
    }
    __syncthreads();

    // phase 3: stable placement, one thread per group (serial within group,
    // groups are in ascending index order -> globally stable)
    if (t < 32) {
        int base = t * 128;
        for (int e = 0; e < 128; ++e) {
            int v = sb[base + e];
            int p = cnt[t][v]++;
            outp[p] = base + e;
        }
    }
}

// ---------------------------------------------------------------------------
// Split-bf16 MFMA GEMM (NT): Y[m][n] = sum_k X[m][k]*W[n][k] + bias[n]
// ---------------------------------------------------------------------------
__global__ __launch_bounds__(256) void gemm_mfma_kernel(
    const u16* __restrict__ Xh, const u16* __restrict__ Xl,
    const u16* __restrict__ Wh, const u16* __restrict__ Wl,
    const float* __restrict__ bias, float* __restrict__ Y)
{
    __shared__ u16 lds[4 * 4096];          // Ah | Al | Bh | Bl, 8KB each
    u16* ldsAh = lds;
    u16* ldsAl = lds + 4096;
    u16* ldsBh = lds + 8192;
    u16* ldsBl = lds + 12288;
    int t = threadIdx.x;
    int lane = t & 63, wave = t >> 6;
    int m0 = blockIdx.y * 128, n0 = blockIdx.x * 128;
    int wm = (wave & 1) * 64, wn = (wave >> 1) * 64;
    f32x4 acc[4][4] = {};

    for (int kt = 0; kt < EDIM; kt += 32) {
        __syncthreads();
#pragma unroll
        for (int it = 0; it < 2; ++it) {
            int g = wave * 128 + it * 64 + lane;        // chunk id 0..511
            int row = ((g >> 6) << 4) | (g & 15);       // s*16 + m
            int kcol = kt + ((g >> 4) & 3) * 8;         // khalf*8
            int lo = (wave * 128 + it * 64) * 8;        // u16 offset (wave-uniform)
            GLL(Xh + (size_t)(m0 + row) * EDIM + kcol, ldsAh + lo);
            GLL(Xl + (size_t)(m0 + row) * EDIM + kcol, ldsAl + lo);
            GLL(Wh + (size_t)(n0 + row) * EDIM + kcol, ldsBh + lo);
            GLL(Wl + (size_t)(n0 + row) * EDIM + kcol, ldsBl + lo);
        }
        __syncthreads();

        int sA = wm >> 4, sB = wn >> 4;
        bf16x8 ah[4], al[4], bh[4], bl[4];
#pragma unroll
        for (int i = 0; i < 4; ++i) {
            ah[i] = *(const bf16x8*)(ldsAh + ((sA + i) * 64 + lane) * 8);
            al[i] = *(const bf16x8*)(ldsAl + ((sA + i) * 64 + lane) * 8);
            bh[i] = *(const bf16x8*)(ldsBh + ((sB + i) * 64 + lane) * 8);
            bl[i] = *(const bf16x8*)(ldsBl + ((sB + i) * 64 + lane) * 8);
        }
#pragma unroll
        for (int i = 0; i < 4; ++i)
#pragma unroll
            for (int j = 0; j < 4; ++j) {
                acc[i][j] = MFMA(ah[i], bh[j], acc[i][j]);
                acc[i][j] = MFMA(ah[i], bl[j], acc[i][j]);
                acc[i][j] = MFMA(al[i], bh[j], acc[i][j]);
            }
    }

    int col_in = lane & 15, rquad = lane >> 4;
#pragma unroll
    for (int j = 0; j < 4; ++j) {
        int col = n0 + wn + j * 16 + col_in;
        float bv = bias[col];
#pragma unroll
        for (int i = 0; i < 4; ++i) {
            int mbase = m0 + wm + i * 16 + rquad * 4;
#pragma unroll
            for (int r = 0; r < 4; ++r)
                Y[(size_t)(mbase + r) * EDIM + col] = acc[i][j][r] + bv;
        }
    }
}

// ---------------------------------------------------------------------------
// MFMA flash attention for one scale (chunk C). Block = 128 sorted queries
// (4 waves x 2 16-query MFMA tiles), grid = (NTOK/128, B*H).
// ---------------------------------------------------------------------------
template <int C>
__global__ __launch_bounds__(256, 3) void attn_mfma_kernel(
    const float* __restrict__ Q, const float* __restrict__ K,
    const float* __restrict__ V, const int* __restrict__ sidx,
    float* __restrict__ out)
{
    __shared__ u16 KfH[4096], KfL[4096], VfH[4096];
    __shared__ u16 PbH[4 * 768], PbL[4 * 768];     // per-wave P relayout, row stride 48

    int t = threadIdx.x;
    int lane = t & 63, wave = t >> 6;
    int quad = lane >> 4, l16 = lane & 15;
    int bh = blockIdx.y, b = bh >> 4, h = bh & 15;
    int p0 = blockIdx.x * 128;
    const int* sxb = sidx + b * NTOK;

    int ptile[2], ws_[2], we_[2];
    bf16x8 qh[2][2], ql[2][2];
#pragma unroll
    for (int tq = 0; tq < 2; ++tq) {
        ptile[tq] = p0 + wave * 32 + tq * 16;
        int c = ptile[tq] / C;
        ws_[tq] = (c > 0) ? (c - 1) * C : 0;
        we_[tq] = (c + 1) * C;
        int qrow = sxb[ptile[tq] + l16];
        const float* qp = Q + ((size_t)(b * NTOK + qrow)) * EDIM + h * HDIM;
#pragma unroll
        for (int kk = 0; kk < 2; ++kk) {
            float4 f0 = *(const float4*)(qp + kk * 32 + quad * 8);
            float4 f1 = *(const float4*)(qp + kk * 32 + quad * 8 + 4);
            float fa[8] = {f0.x, f0.y, f0.z, f0.w, f1.x, f1.y, f1.z, f1.w};
            bf16x8 hv, lv;
#pragma unroll
            for (int e = 0; e < 8; ++e) {
                u16 hh, ll;
                split2(fa[e] * 0.125f, hh, ll);
                hv[e] = (short)hh; lv[e] = (short)ll;
            }
            qh[tq][kk] = hv; ql[tq][kk] = lv;
        }
    }

    f32x4 oacc[2][4] = {};
    float lpart[2][4] = {};
    float mrun[2] = {-1e30f, -1e30f};

    int c0 = p0 / C, c1 = (p0 + 127) / C;
    int kmin = (c0 > 0) ? (c0 - 1) * C : 0;
    int kmax = (c1 + 1) * C;

    for (int ks = kmin; ks < kmax; ks += 64) {
        int nk = min(64, kmax - ks);
        __syncthreads();
#pragma unroll
        for (int it = 0; it < 4; ++it) {
            int idx = it * 256 + t;          // 0..1023
            int key = idx >> 4, d4 = idx & 15;
            int d = d4 * 4;
            int vbase0 = ((key >> 5) * 2048) + (((key >> 3) & 3) * 128) + (key & 7);
            if (key < nk) {
                int tok = sxb[ks + key];
                size_t rowo = ((size_t)(b * NTOK + tok)) * EDIM + h * HDIM + d;
                float4 fk = *(const float4*)(K + rowo);
                float4 fv = *(const float4*)(V + rowo);
                int kk = d >> 5, qd = (d >> 3) & 3, j = d & 7;
                int kbase = (((key >> 4) * 2 + kk) * 64 + qd * 16 + (key & 15)) * 8 + j;
                ushort4 hh, ll;
                split2(fk.x, hh.x, ll.x); split2(fk.y, hh.y, ll.y);
                split2(fk.z, hh.z, ll.z); split2(fk.w, hh.w, ll.w);
                *(ushort4*)(KfH + kbase) = hh;
                *(ushort4*)(KfL + kbase) = ll;
                float fva[4] = {fv.x, fv.y, fv.z, fv.w};
#pragma unroll
                for (int e = 0; e < 4; ++e) {
                    int dim = d + e;
                    VfH[vbase0 + (dim >> 4) * 512 + (dim & 15) * 8] = bf16rne(fva[e]);
                }
            } else {
#pragma unroll
                for (int e = 0; e < 4; ++e) {
                    int dim = d + e;
                    VfH[vbase0 + (dim >> 4) * 512 + (dim & 15) * 8] = 0;
                }
            }
        }
        __syncthreads();

        int jlo0 = max(ks, ws_[0]) - ks, jhi0 = min(ks + nk, we_[0]) - ks;
        int jlo1 = max(ks, ws_[1]) - ks, jhi1 = min(ks + nk, we_[1]) - ks;
        bool e0 = jlo0 < jhi0, e1 = jlo1 < jhi1;
        if (!e0 && !e1) continue;
        int glo = e0 ? (e1 ? min(jlo0, jlo1) : jlo0) : jlo1;
        int ghi = e0 ? (e1 ? max(jhi0, jhi1) : jhi0) : jhi1;

        for (int g0 = glo & ~31; g0 < ghi; g0 += 32) {
            int s0i = g0 >> 4;
            int s1i = min(s0i + 1, 3);
            bf16x8 kh0[2], kl0[2], kh1[2], kl1[2];
#pragma unroll
            for (int kk = 0; kk < 2; ++kk) {
                kh0[kk] = *(const bf16x8*)(KfH + ((s0i * 2 + kk) * 64 + lane) * 8);
                kl0[kk] = *(const bf16x8*)(KfL + ((s0i * 2 + kk) * 64 + lane) * 8);
                kh1[kk] = *(const bf16x8*)(KfH + ((s1i * 2 + kk) * 64 + lane) * 8);
                kl1[kk] = *(const bf16x8*)(KfL + ((s1i * 2 + kk) * 64 + lane) * 8);
            }
#pragma unroll
            for (int tq = 0; tq < 2; ++tq) {
                int jl = tq ? jlo1 : jlo0, jh = tq ? jhi1 : jhi0;
                bool v0 = (g0 >= jl) && (g0 < jh);
                bool v1 = (g0 + 16 >= jl) && (g0 + 16 < jh);
                if (!v0 && !v1) continue;
                f32x4 sa = {0.f, 0.f, 0.f, 0.f}, sb2 = {0.f, 0.f, 0.f, 0.f};
                if (v0) {
                    sa = MFMA(qh[tq][0], kh0[0], sa);
                    sa = MFMA(qh[tq][0], kl0[0], sa);
                    sa = MFMA(ql[tq][0], kh0[0], sa);
                    sa = MFMA(qh[tq][1], kh0[1], sa);
                    sa = MFMA(qh[tq][1], kl0[1], sa);
                    sa = MFMA(ql[tq][1], kh0[1], sa);
                }
                if (v1) {
                    sb2 = MFMA(qh[tq][0], kh1[0], sb2);
                    sb2 = MFMA(qh[tq][0], kl1[0], sb2);
                    sb2 = MFMA(ql[tq][0], kh1[0], sb2);
                    sb2 = MFMA(qh[tq][1], kh1[1], sb2);
                    sb2 = MFMA(qh[tq][1], kl1[1], sb2);
                    sb2 = MFMA(ql[tq][1], kh1[1], sb2);
                }
                float smax = -1e30f;
                if (v0) smax = fmaxf(smax, fmaxf(fmaxf(sa[0], sa[1]), fmaxf(sa[2], sa[3])));
                if (v1) smax = fmaxf(smax, fmaxf(fmaxf(sb2[0], sb2[1]), fmaxf(sb2[2], sb2[3])));
                smax = fmaxf(smax, __shfl_xor(smax, 1));
                smax = fmaxf(smax, __shfl_xor(smax, 2));
                smax = fmaxf(smax, __shfl_xor(smax, 4));
                smax = fmaxf(smax, __shfl_xor(smax, 8));
                float mold = mrun[tq];
                float mnew = fmaxf(mold, smax);
                mrun[tq] = mnew;
                float alpha = __expf(mold - mnew);
#pragma unroll
                for (int r = 0; r < 4; ++r) lpart[tq][r] *= alpha;
#pragma unroll
                for (int dt = 0; dt < 4; ++dt) {
                    oacc[tq][dt][0] *= alpha; oacc[tq][dt][1] *= alpha;
                    oacc[tq][dt][2] *= alpha; oacc[tq][dt][3] *= alpha;
                }
                u16* pbh = PbH + wave * 768;
                u16* pbl = PbL + wave * 768;
#pragma unroll
                for (int r = 0; r < 4; ++r) {
                    float pa = v0 ? __expf(sa[r] - mnew) : 0.f;
                    float pb = v1 ? __expf(sb2[r] - mnew) : 0.f;
                    lpart[tq][r] += pa + pb;
                    u16 hh, ll;
                    split2(pa, hh, ll);
                    pbh[(quad * 4 + r) * 48 + l16] = hh;
                    pbl[(quad * 4 + r) * 48 + l16] = ll;
                    split2(pb, hh, ll);
                    pbh[(quad * 4 + r) * 48 + 16 + l16] = hh;
                    pbl[(quad * 4 + r) * 48 + 16 + l16] = ll;
                }
                bf16x8 ph = *(const bf16x8*)(pbh + l16 * 48 + quad * 8);
                bf16x8 pl = *(const bf16x8*)(pbl + l16 * 48 + quad * 8);
                int vbase = (g0 >> 5) * 2048;
#pragma unroll
                for (int dt = 0; dt < 4; ++dt) {
                    bf16x8 vv = *(const bf16x8*)(VfH + vbase + dt * 512 + lane * 8);
                    oacc[tq][dt] = MFMA(ph, vv, oacc[tq][dt]);
                    oacc[tq][dt] = MFMA(pl, vv, oacc[tq][dt]);
                }
            }
        }
    }

#pragma unroll
    for (int tq = 0; tq < 2; ++tq) {
        float inv[4];
#pragma unroll
        for (int r = 0; r < 4; ++r) {
            float v = lpart[tq][r];
            v += __shfl_xor(v, 1);
            v += __shfl_xor(v, 2);
            v += __shfl_xor(v, 4);
            v += __shfl_xor(v, 8);
            inv[r] = 1.0f / (3.0f * v);
        }
#pragma unroll
        for (int r = 0; r < 4; ++r) {
            int tok = sxb[ptile[tq] + quad * 4 + r];
            float* op = out + ((size_t)(b * NTOK + tok)) * EDIM + h * HDIM + l16;
#pragma unroll
            for (int dt = 0; dt < 4; ++dt)
                op[dt * 16] += oacc[tq][dt][r] * inv[r];
        }
    }
}

// ---------------------------------------------------------------------------
extern "C" void kernel_launch(void* const* d_in, const int* in_sizes, int n_in,
                              void* d_out, int out_size, void* d_ws, size_t ws_size,
                              hipStream_t stream)
{
    const float* x   = (const float*)d_in[0];
    const int*   wbc = (const int*)d_in[1];
    const int*   wbm = (const int*)d_in[2];
    const int*   wbf = (const int*)d_in[3];
    const float* Wq = (const float*)d_in[4],  *bq = (const float*)d_in[5];
    const float* Aq = (const float*)d_in[6],  *Bq = (const float*)d_in[7];
    const float* Wk = (const float*)d_in[8],  *bk = (const float*)d_in[9];
    const float* Ak = (const float*)d_in[10], *Bk = (const float*)d_in[11];
    const float* Wv = (const float*)d_in[12], *bv = (const float*)d_in[13];
    const float* Av = (const float*)d_in[14], *Bv = (const float*)d_in[15];
    const float* Wo = (const float*)d_in[16], *bo = (const float*)d_in[17];
    const float* Ao = (const float*)d_in[18], *Bo = (const float*)d_in[19];

    const size_t EE  = (size_t)EDIM * EDIM;        // 1,048,576
    const size_t BNE = (size_t)MROWS * EDIM;       // 8,388,608

    char* wsb = (char*)d_ws;
    float* qb = (float*)wsb;                        wsb += BNE * 4;
    float* kb = (float*)wsb;                        wsb += BNE * 4;
    float* vb = (float*)wsb;                        wsb += BNE * 4;
    float* ab = (float*)wsb;                        wsb += BNE * 4;
    u16* xh = (u16*)wsb;                            wsb += BNE * 2;   // also abh
    u16* xl = (u16*)wsb;                            wsb += BNE * 2;   // also abl
    u16* wsp = (u16*)wsb;                           wsb += 8 * EE * 2;
    int* sidx = (int*)wsb;                          wsb += 3 * BDIM * NTOK * 4;

    u16* wqh = wsp + 0 * EE, *wql = wsp + 1 * EE;
    u16* wkh = wsp + 2 * EE, *wkl = wsp + 3 * EE;
    u16* wvh = wsp + 4 * EE, *wvl = wsp + 5 * EE;
    u16* woh = wsp + 6 * EE, *wol = wsp + 7 * EE;

    // attention accumulator must start at zero (ws is poisoned each call)
    hipMemsetAsync(ab, 0, BNE * sizeof(float), stream);

    split_kernel<<<BNE / 1024, 256, 0, stream>>>(x, xh, xl);

    build_weff_kernel<<<4096, 256, 0, stream>>>(Wq, Aq, Bq, wqh, wql);
    build_weff_kernel<<<4096, 256, 0, stream>>>(Wk, Ak, Bk, wkh, wkl);
    build_weff_kernel<<<4096, 256, 0, stream>>>(Wv, Av, Bv, wvh, wvl);
    build_weff_kernel<<<4096, 256, 0, stream>>>(Wo, Ao, Bo, woh, wol);

    sort3_kernel<<<dim3(BDIM, 3), 256, 0, stream>>>(wbc, wbm, wbf, sidx);

    dim3 gg(EDIM / 128, MROWS / 128);   // (8, 64)
    gemm_mfma_kernel<<<gg, 256, 0, stream>>>(xh, xl, wqh, wql, bq, qb);
    gemm_mfma_kernel<<<gg, 256, 0, stream>>>(xh, xl, wkh, wkl, bk, kb);
    gemm_mfma_kernel<<<gg, 256, 0, stream>>>(xh, xl, wvh, wvl, bv, vb);

    dim3 ga(NTOK / 128, BDIM * HEADS);  // (32, 32)
    attn_mfma_kernel<256><<<ga, 256, 0, stream>>>(qb, kb, vb, sidx + 0 * BDIM * NTOK, ab);
    attn_mfma_kernel<64><<<ga, 256, 0, stream>>>(qb, kb, vb, sidx + 1 * BDIM * NTOK, ab);
    attn_mfma_kernel<16><<<ga, 256, 0, stream>>>(qb, kb, vb, sidx + 2 * BDIM * NTOK, ab);

    // reuse xh/xl space for the attention-output split
    split_kernel<<<BNE / 1024, 256, 0, stream>>>(ab, xh, xl);
    gemm_mfma_kernel<<<gg, 256, 0, stream>>>(xh, xl, woh, wol, bo, (float*)d_out);
}

// Round 5
// 621.687 us; speedup vs baseline: 3.8209x; 1.0866x over previous
//
#include <hip/hip_runtime.h>
#include <cstdint>
#include <cstddef>

// Problem constants
#define BDIM 2
#define NTOK 4096
#define EDIM 1024
#define HEADS 16
#define HDIM 64
#define MROWS (BDIM * NTOK)   // 8192

typedef unsigned short u16;
typedef __attribute__((ext_vector_type(8))) short bf16x8;   // 8 bf16 = 4 VGPR
typedef __attribute__((ext_vector_type(4))) float f32x4;

#define MFMA(a, b, c) __builtin_amdgcn_mfma_f32_16x16x32_bf16(a, b, c, 0, 0, 0)

// round-to-nearest-even split of fp32 into hi/lo bf16
__device__ inline void split2(float x, u16& h, u16& l) {
    union { float f; unsigned u; } a;
    a.f = x;
    unsigned uh = a.u + 0x7fff + ((a.u >> 16) & 1);
    h = (u16)(uh >> 16);
    union { unsigned u; float f; } hf; hf.u = (unsigned)h << 16;
    a.f = x - hf.f;
    unsigned ul = a.u + 0x7fff + ((a.u >> 16) & 1);
    l = (u16)(ul >> 16);
}

__device__ inline u16 bf16rne(float x) {
    union { float f; unsigned u; } a; a.f = x;
    unsigned r = a.u + 0x7fff + ((a.u >> 16) & 1);
    return (u16)(r >> 16);
}

// global -> LDS direct 16B staging (lane i lands at lds_base + i*16)
#define GLL(gp, lp) __builtin_amdgcn_global_load_lds( \
    (const __attribute__((address_space(1))) unsigned*)(gp), \
    (__attribute__((address_space(3))) unsigned*)(lp), 16, 0, 0)

// ---------------------------------------------------------------------------
// W_eff = W + 2*B@A, emitted directly as hi/lo bf16 pair
// ---------------------------------------------------------------------------
__global__ __launch_bounds__(256) void build_weff_kernel(
    const float* __restrict__ W, const float* __restrict__ A,
    const float* __restrict__ Bm, u16* __restrict__ dh, u16* __restrict__ dl)
{
    int idx = blockIdx.x * 256 + threadIdx.x;      // over E*E
    int o = idx >> 10, i = idx & 1023;
    float s = 0.f;
#pragma unroll
    for (int r = 0; r < 8; ++r) s += Bm[o * 8 + r] * A[r * 1024 + i];
    float w = W[idx] + 2.0f * s;
    u16 h, l;
    split2(w, h, l);
    dh[idx] = h; dl[idx] = l;
}

// ---------------------------------------------------------------------------
// fp32 buffer -> hi/lo bf16 buffers, 4 elements / thread
// ---------------------------------------------------------------------------
__global__ __launch_bounds__(256) void split_kernel(
    const float* __restrict__ src, u16* __restrict__ dh, u16* __restrict__ dl)
{
    int idx = blockIdx.x * 256 + threadIdx.x;      // one float4
    float4 v = ((const float4*)src)[idx];
    ushort4 h, l;
    split2(v.x, h.x, l.x);
    split2(v.y, h.y, l.y);
    split2(v.z, h.z, l.z);
    split2(v.w, h.w, l.w);
    ((ushort4*)dh)[idx] = h;
    ((ushort4*)dl)[idx] = l;
}

// ---------------------------------------------------------------------------
// Parallel stable counting sort, 3 scales x BDIM batches. grid=(BDIM,3).
// ---------------------------------------------------------------------------
__global__ __launch_bounds__(256) void sort3_kernel(
    const int* __restrict__ w0, const int* __restrict__ w1,
    const int* __restrict__ w2, int* __restrict__ sidx)
{
    __shared__ int sb[NTOK];          // 16 KB
    __shared__ int cnt[32][256];      // 32 KB
    __shared__ int gb[256];           // 1 KB
    const int* srcs[3] = {w0, w1, w2};
    int t = threadIdx.x;
    const int* w = srcs[blockIdx.y] + blockIdx.x * NTOK;
    int* outp = sidx + ((int)blockIdx.y * BDIM + (int)blockIdx.x) * NTOK;

    for (int i = t; i < NTOK; i += 256) sb[i] = w[i];
    for (int i = t; i < 32 * 256; i += 256) ((int*)cnt)[i] = 0;
    __syncthreads();

    int g = t >> 3;
#pragma unroll
    for (int e = 0; e < 16; ++e)
        atomicAdd(&cnt[g][sb[g * 128 + (t & 7) + 8 * e]], 1);
    __syncthreads();

    int run = 0;
#pragma unroll
    for (int gg = 0; gg < 32; ++gg) {
        int c = cnt[gg][t];
        cnt[gg][t] = run;
        run += c;
    }
    gb[t] = run;
    __syncthreads();
    if (t == 0) {
        int acc = 0;
        for (int v = 0; v < 256; ++v) { int c = gb[v]; gb[v] = acc; acc += c; }
    }
    __syncthreads();
    for (int i = t; i < 32 * 256; i += 256) {
        int v = i & 255, gg = i >> 8;
        cnt[gg][v] += gb[v];
    }
    __syncthreads();

    if (t < 32) {
        int base = t * 128;
        for (int e = 0; e < 128; ++e) {
            int v = sb[base + e];
            int p = cnt[t][v]++;
            outp[p] = base + e;
        }
    }
}

// ---------------------------------------------------------------------------
// Fused QKV split-bf16 MFMA GEMM: N = 3072 (Wh/Wl = [wq|wk|wv] stacked).
// Emits split-bf16 outputs directly: Q -> (qh,ql) scaled by 1/8, K -> (kh,kl),
// V -> vh only. grid = (3072/128, MROWS/128)
// ---------------------------------------------------------------------------
__global__ __launch_bounds__(256) void gemm_qkv_kernel(
    const u16* __restrict__ Xh, const u16* __restrict__ Xl,
    const u16* __restrict__ Wh, const u16* __restrict__ Wl,
    const float* __restrict__ bq, const float* __restrict__ bk,
    const float* __restrict__ bv,
    u16* __restrict__ qh, u16* __restrict__ ql,
    u16* __restrict__ kh, u16* __restrict__ kl, u16* __restrict__ vh)
{
    __shared__ u16 lds[4 * 4096];          // Ah | Al | Bh | Bl, 8KB each
    u16* ldsAh = lds;
    u16* ldsAl = lds + 4096;
    u16* ldsBh = lds + 8192;
    u16* ldsBl = lds + 12288;
    int t = threadIdx.x;
    int lane = t & 63, wave = t >> 6;
    int m0 = blockIdx.y * 128, n0 = blockIdx.x * 128;
    int wm = (wave & 1) * 64, wn = (wave >> 1) * 64;
    f32x4 acc[4][4] = {};

    for (int kt = 0; kt < EDIM; kt += 32) {
        __syncthreads();
#pragma unroll
        for (int it = 0; it < 2; ++it) {
            int g = wave * 128 + it * 64 + lane;
            int row = ((g >> 6) << 4) | (g & 15);
            int kcol = kt + ((g >> 4) & 3) * 8;
            int lo = (wave * 128 + it * 64) * 8;
            GLL(Xh + (size_t)(m0 + row) * EDIM + kcol, ldsAh + lo);
            GLL(Xl + (size_t)(m0 + row) * EDIM + kcol, ldsAl + lo);
            GLL(Wh + (size_t)(n0 + row) * EDIM + kcol, ldsBh + lo);
            GLL(Wl + (size_t)(n0 + row) * EDIM + kcol, ldsBl + lo);
        }
        __syncthreads();

        int sA = wm >> 4, sB = wn >> 4;
        bf16x8 ah[4], al[4], bh[4], bl[4];
#pragma unroll
        for (int i = 0; i < 4; ++i) {
            ah[i] = *(const bf16x8*)(ldsAh + ((sA + i) * 64 + lane) * 8);
            al[i] = *(const bf16x8*)(ldsAl + ((sA + i) * 64 + lane) * 8);
            bh[i] = *(const bf16x8*)(ldsBh + ((sB + i) * 64 + lane) * 8);
            bl[i] = *(const bf16x8*)(ldsBl + ((sB + i) * 64 + lane) * 8);
        }
#pragma unroll
        for (int i = 0; i < 4; ++i)
#pragma unroll
            for (int j = 0; j < 4; ++j) {
                acc[i][j] = MFMA(ah[i], bh[j], acc[i][j]);
                acc[i][j] = MFMA(ah[i], bl[j], acc[i][j]);
                acc[i][j] = MFMA(al[i], bh[j], acc[i][j]);
            }
    }

    int proj = n0 >> 10;                    // 0=Q, 1=K, 2=V (block-uniform)
    const float* bias = (proj == 0) ? bq : (proj == 1) ? bk : bv;
    u16* oh = (proj == 0) ? qh : kh;
    u16* ol = (proj == 0) ? ql : kl;
    int col_in = lane & 15, rquad = lane >> 4;
#pragma unroll
    for (int j = 0; j < 4; ++j) {
        int coll = (n0 & 1023) + wn + j * 16 + col_in;
        float bv_ = bias[coll];
#pragma unroll
        for (int i = 0; i < 4; ++i) {
            int mbase = m0 + wm + i * 16 + rquad * 4;
#pragma unroll
            for (int r = 0; r < 4; ++r) {
                float val = acc[i][j][r] + bv_;
                size_t off = (size_t)(mbase + r) * EDIM + coll;
                if (proj == 2) {
                    vh[off] = bf16rne(val);
                } else {
                    u16 hh, ll;
                    split2((proj == 0) ? val * 0.125f : val, hh, ll);
                    oh[off] = hh; ol[off] = ll;
                }
            }
        }
    }
}

// ---------------------------------------------------------------------------
// Split-bf16 MFMA GEMM (NT), fp32 out — used for the final O projection.
// ---------------------------------------------------------------------------
__global__ __launch_bounds__(256) void gemm_mfma_kernel(
    const u16* __restrict__ Xh, const u16* __restrict__ Xl,
    const u16* __restrict__ Wh, const u16* __restrict__ Wl,
    const float* __restrict__ bias, float* __restrict__ Y)
{
    __shared__ u16 lds[4 * 4096];
    u16* ldsAh = lds;
    u16* ldsAl = lds + 4096;
    u16* ldsBh = lds + 8192;
    u16* ldsBl = lds + 12288;
    int t = threadIdx.x;
    int lane = t & 63, wave = t >> 6;
    int m0 = blockIdx.y * 128, n0 = blockIdx.x * 128;
    int wm = (wave & 1) * 64, wn = (wave >> 1) * 64;
    f32x4 acc[4][4] = {};

    for (int kt = 0; kt < EDIM; kt += 32) {
        __syncthreads();
#pragma unroll
        for (int it = 0; it < 2; ++it) {
            int g = wave * 128 + it * 64 + lane;
            int row = ((g >> 6) << 4) | (g & 15);
            int kcol = kt + ((g >> 4) & 3) * 8;
            int lo = (wave * 128 + it * 64) * 8;
            GLL(Xh + (size_t)(m0 + row) * EDIM + kcol, ldsAh + lo);
            GLL(Xl + (size_t)(m0 + row) * EDIM + kcol, ldsAl + lo);
            GLL(Wh + (size_t)(n0 + row) * EDIM + kcol, ldsBh + lo);
            GLL(Wl + (size_t)(n0 + row) * EDIM + kcol, ldsBl + lo);
        }
        __syncthreads();

        int sA = wm >> 4, sB = wn >> 4;
        bf16x8 ah[4], al[4], bh[4], bl[4];
#pragma unroll
        for (int i = 0; i < 4; ++i) {
            ah[i] = *(const bf16x8*)(ldsAh + ((sA + i) * 64 + lane) * 8);
            al[i] = *(const bf16x8*)(ldsAl + ((sA + i) * 64 + lane) * 8);
            bh[i] = *(const bf16x8*)(ldsBh + ((sB + i) * 64 + lane) * 8);
            bl[i] = *(const bf16x8*)(ldsBl + ((sB + i) * 64 + lane) * 8);
        }
#pragma unroll
        for (int i = 0; i < 4; ++i)
#pragma unroll
            for (int j = 0; j < 4; ++j) {
                acc[i][j] = MFMA(ah[i], bh[j], acc[i][j]);
                acc[i][j] = MFMA(ah[i], bl[j], acc[i][j]);
                acc[i][j] = MFMA(al[i], bh[j], acc[i][j]);
            }
    }

    int col_in = lane & 15, rquad = lane >> 4;
#pragma unroll
    for (int j = 0; j < 4; ++j) {
        int col = n0 + wn + j * 16 + col_in;
        float bv = bias[col];
#pragma unroll
        for (int i = 0; i < 4; ++i) {
            int mbase = m0 + wm + i * 16 + rquad * 4;
#pragma unroll
            for (int r = 0; r < 4; ++r)
                Y[(size_t)(mbase + r) * EDIM + col] = acc[i][j][r] + bv;
        }
    }
}

// ---------------------------------------------------------------------------
// MFMA flash attention v2. Inputs pre-split bf16 (qh scaled, kh/kl, vh).
// K staged via global_load_lds (gathered per-lane addresses, fragment order);
// V transposed into [dim][key] stride-72 LDS; P hi-only relayout (stride 56).
// Block = 128 sorted queries, grid = (NTOK/128, B*H).
// ---------------------------------------------------------------------------
template <int C>
__global__ __launch_bounds__(256, 3) void attn_mfma_kernel(
    const u16* __restrict__ Qh, const u16* __restrict__ Ql,
    const u16* __restrict__ Kh, const u16* __restrict__ Kl,
    const u16* __restrict__ Vh, const int* __restrict__ sidx,
    float* __restrict__ out)
{
    __shared__ u16 KfH[4096], KfL[4096];   // [s(4)][kk(2)][lane(64)][8]
    __shared__ u16 VL[64 * 72];            // [dim(64)][key(64)] stride 72
    __shared__ u16 PbH[4 * 16 * 56];       // per-wave P, row stride 56

    int t = threadIdx.x;
    int lane = t & 63, wave = t >> 6;
    int quad = lane >> 4, l16 = lane & 15;
    int bh = blockIdx.y, b = bh >> 4, h = bh & 15;
    int p0 = blockIdx.x * 128;
    const int* sxb = sidx + b * NTOK;

    // ---- per-tile setup: windows + Q fragments (pre-scaled, pre-split) ----
    int ptile[2], ws_[2], we_[2];
    bf16x8 qhf[2][2], qlf[2][2];
#pragma unroll
    for (int tq = 0; tq < 2; ++tq) {
        ptile[tq] = p0 + wave * 32 + tq * 16;
        int c = ptile[tq] / C;
        ws_[tq] = (c > 0) ? (c - 1) * C : 0;
        we_[tq] = (c + 1) * C;
        int qrow = sxb[ptile[tq] + l16];
        size_t rb = (size_t)(b * NTOK + qrow) * EDIM + h * HDIM + quad * 8;
#pragma unroll
        for (int kk = 0; kk < 2; ++kk) {
            qhf[tq][kk] = *(const bf16x8*)(Qh + rb + kk * 32);
            qlf[tq][kk] = *(const bf16x8*)(Ql + rb + kk * 32);
        }
    }

    f32x4 oacc[2][4] = {};
    float lpart[2][4] = {};
    float mrun[2] = {-1e30f, -1e30f};

    int c0 = p0 / C, c1 = (p0 + 127) / C;
    int kmin = (c0 > 0) ? (c0 - 1) * C : 0;
    int kmax = (c1 + 1) * C;

    for (int ks = kmin; ks < kmax; ks += 64) {
        int nk = min(64, kmax - ks);
        __syncthreads();                     // previous slab fully consumed

        // ---- K staging: async direct-to-LDS in fragment order ----
        {
            int key16 = lane & 15, qd = lane >> 4;
            int tok = sxb[min(ks + wave * 16 + key16, NTOK - 1)];
            size_t rb = (size_t)(b * NTOK + tok) * EDIM + h * HDIM + qd * 8;
            GLL(Kh + rb,      KfH + (wave * 2 + 0) * 512);
            GLL(Kh + rb + 32, KfH + (wave * 2 + 1) * 512);
            GLL(Kl + rb,      KfL + (wave * 2 + 0) * 512);
            GLL(Kl + rb + 32, KfL + (wave * 2 + 1) * 512);
        }
        // ---- V staging: bf16 load + LDS transpose ([dim][key], 2-way free) --
#pragma unroll
        for (int it = 0; it < 2; ++it) {
            int c = it * 256 + t;            // 0..511
            int key = c & 63, dg = c >> 6;
            int tok = sxb[min(ks + key, NTOK - 1)];
            bf16x8 vv = *(const bf16x8*)(Vh + (size_t)(b * NTOK + tok) * EDIM + h * HDIM + dg * 8);
#pragma unroll
            for (int e = 0; e < 8; ++e)
                VL[(dg * 8 + e) * 72 + key] = (u16)vv[e];
        }
        __syncthreads();

        int jlo0 = max(ks, ws_[0]) - ks, jhi0 = min(ks + nk, we_[0]) - ks;
        int jlo1 = max(ks, ws_[1]) - ks, jhi1 = min(ks + nk, we_[1]) - ks;
        bool e0 = jlo0 < jhi0, e1 = jlo1 < jhi1;
        if (!e0 && !e1) continue;
        int glo = e0 ? (e1 ? min(jlo0, jlo1) : jlo0) : jlo1;
        int ghi = e0 ? (e1 ? max(jhi0, jhi1) : jhi0) : jhi1;

        for (int g0 = glo & ~31; g0 < ghi; g0 += 32) {
            int s0i = g0 >> 4;
            int s1i = min(s0i + 1, 3);
            bf16x8 kh0[2], kl0[2], kh1[2], kl1[2];
#pragma unroll
            for (int kk = 0; kk < 2; ++kk) {
                kh0[kk] = *(const bf16x8*)(KfH + ((s0i * 2 + kk) * 64 + lane) * 8);
                kl0[kk] = *(const bf16x8*)(KfL + ((s0i * 2 + kk) * 64 + lane) * 8);
                kh1[kk] = *(const bf16x8*)(KfH + ((s1i * 2 + kk) * 64 + lane) * 8);
                kl1[kk] = *(const bf16x8*)(KfL + ((s1i * 2 + kk) * 64 + lane) * 8);
            }
#pragma unroll
            for (int tq = 0; tq < 2; ++tq) {
                int jl = tq ? jlo1 : jlo0, jh = tq ? jhi1 : jhi0;
                bool v0 = (g0 >= jl) && (g0 < jh);
                bool v1 = (g0 + 16 >= jl) && (g0 + 16 < jh);
                if (!v0 && !v1) continue;
                f32x4 sa = {0.f, 0.f, 0.f, 0.f}, sb2 = {0.f, 0.f, 0.f, 0.f};
                if (v0) {
                    sa = MFMA(qhf[tq][0], kh0[0], sa);
                    sa = MFMA(qhf[tq][0], kl0[0], sa);
                    sa = MFMA(qlf[tq][0], kh0[0], sa);
                    sa = MFMA(qhf[tq][1], kh0[1], sa);
                    sa = MFMA(qhf[tq][1], kl0[1], sa);
                    sa = MFMA(qlf[tq][1], kh0[1], sa);
                }
                if (v1) {
                    sb2 = MFMA(qhf[tq][0], kh1[0], sb2);
                    sb2 = MFMA(qhf[tq][0], kl1[0], sb2);
                    sb2 = MFMA(qlf[tq][0], kh1[0], sb2);
                    sb2 = MFMA(qhf[tq][1], kh1[1], sb2);
                    sb2 = MFMA(qhf[tq][1], kl1[1], sb2);
                    sb2 = MFMA(qlf[tq][1], kh1[1], sb2);
                }
                float smax = -1e30f;
                if (v0) smax = fmaxf(smax, fmaxf(fmaxf(sa[0], sa[1]), fmaxf(sa[2], sa[3])));
                if (v1) smax = fmaxf(smax, fmaxf(fmaxf(sb2[0], sb2[1]), fmaxf(sb2[2], sb2[3])));
                smax = fmaxf(smax, __shfl_xor(smax, 1));
                smax = fmaxf(smax, __shfl_xor(smax, 2));
                smax = fmaxf(smax, __shfl_xor(smax, 4));
                smax = fmaxf(smax, __shfl_xor(smax, 8));
                float mold = mrun[tq];
                float mnew = fmaxf(mold, smax);
                mrun[tq] = mnew;
                float alpha = __expf(mold - mnew);
#pragma unroll
                for (int r = 0; r < 4; ++r) lpart[tq][r] *= alpha;
#pragma unroll
                for (int dt = 0; dt < 4; ++dt) {
                    oacc[tq][dt][0] *= alpha; oacc[tq][dt][1] *= alpha;
                    oacc[tq][dt][2] *= alpha; oacc[tq][dt][3] *= alpha;
                }
                u16* pbh = PbH + wave * 896;
#pragma unroll
                for (int r = 0; r < 4; ++r) {
                    float pa = v0 ? __expf(sa[r] - mnew) : 0.f;
                    float pb = v1 ? __expf(sb2[r] - mnew) : 0.f;
                    lpart[tq][r] += pa + pb;
                    pbh[(quad * 4 + r) * 56 + l16] = bf16rne(pa);
                    pbh[(quad * 4 + r) * 56 + 16 + l16] = bf16rne(pb);
                }
                bf16x8 ph = *(const bf16x8*)(pbh + l16 * 56 + quad * 8);
                int kh2 = g0 >> 5;
#pragma unroll
                for (int dt = 0; dt < 4; ++dt) {
                    bf16x8 vv = *(const bf16x8*)(VL + (dt * 16 + l16) * 72 + kh2 * 32 + quad * 8);
                    oacc[tq][dt] = MFMA(ph, vv, oacc[tq][dt]);
                }
            }
        }
    }

#pragma unroll
    for (int tq = 0; tq < 2; ++tq) {
        float inv[4];
#pragma unroll
        for (int r = 0; r < 4; ++r) {
            float v = lpart[tq][r];
            v += __shfl_xor(v, 1);
            v += __shfl_xor(v, 2);
            v += __shfl_xor(v, 4);
            v += __shfl_xor(v, 8);
            inv[r] = 1.0f / (3.0f * v);
        }
#pragma unroll
        for (int r = 0; r < 4; ++r) {
            int tok = sxb[ptile[tq] + quad * 4 + r];
            float* op = out + (size_t)(b * NTOK + tok) * EDIM + h * HDIM + l16;
#pragma unroll
            for (int dt = 0; dt < 4; ++dt)
                op[dt * 16] += oacc[tq][dt][r] * inv[r];
        }
    }
}

// ---------------------------------------------------------------------------
extern "C" void kernel_launch(void* const* d_in, const int* in_sizes, int n_in,
                              void* d_out, int out_size, void* d_ws, size_t ws_size,
                              hipStream_t stream)
{
    const float* x   = (const float*)d_in[0];
    const int*   wbc = (const int*)d_in[1];
    const int*   wbm = (const int*)d_in[2];
    const int*   wbf = (const int*)d_in[3];
    const float* Wq = (const float*)d_in[4],  *bq = (const float*)d_in[5];
    const float* Aq = (const float*)d_in[6],  *Bq = (const float*)d_in[7];
    const float* Wk = (const float*)d_in[8],  *bk = (const float*)d_in[9];
    const float* Ak = (const float*)d_in[10], *Bk = (const float*)d_in[11];
    const float* Wv = (const float*)d_in[12], *bv = (const float*)d_in[13];
    const float* Av = (const float*)d_in[14], *Bv = (const float*)d_in[15];
    const float* Wo = (const float*)d_in[16], *bo = (const float*)d_in[17];
    const float* Ao = (const float*)d_in[18], *Bo = (const float*)d_in[19];

    const size_t EE  = (size_t)EDIM * EDIM;        // 1,048,576
    const size_t BNE = (size_t)MROWS * EDIM;       // 8,388,608

    char* wsb = (char*)d_ws;
    float* ab = (float*)wsb;                        wsb += BNE * 4;   // attn accum
    u16* xh = (u16*)wsb;                            wsb += BNE * 2;   // also abh
    u16* xl = (u16*)wsb;                            wsb += BNE * 2;   // also abl
    u16* qh = (u16*)wsb;                            wsb += BNE * 2;
    u16* ql = (u16*)wsb;                            wsb += BNE * 2;
    u16* kh = (u16*)wsb;                            wsb += BNE * 2;
    u16* kl = (u16*)wsb;                            wsb += BNE * 2;
    u16* vh = (u16*)wsb;                            wsb += BNE * 2;
    u16* wh_all = (u16*)wsb;                        wsb += 3 * EE * 2; // [q|k|v] hi
    u16* wl_all = (u16*)wsb;                        wsb += 3 * EE * 2; // [q|k|v] lo
    u16* woh = (u16*)wsb;                           wsb += EE * 2;
    u16* wol = (u16*)wsb;                           wsb += EE * 2;
    int* sidx = (int*)wsb;                          wsb += 3 * BDIM * NTOK * 4;

    // attention accumulator must start at zero (ws is poisoned each call)
    hipMemsetAsync(ab, 0, BNE * sizeof(float), stream);

    split_kernel<<<BNE / 1024, 256, 0, stream>>>(x, xh, xl);

    build_weff_kernel<<<4096, 256, 0, stream>>>(Wq, Aq, Bq, wh_all + 0 * EE, wl_all + 0 * EE);
    build_weff_kernel<<<4096, 256, 0, stream>>>(Wk, Ak, Bk, wh_all + 1 * EE, wl_all + 1 * EE);
    build_weff_kernel<<<4096, 256, 0, stream>>>(Wv, Av, Bv, wh_all + 2 * EE, wl_all + 2 * EE);
    build_weff_kernel<<<4096, 256, 0, stream>>>(Wo, Ao, Bo, woh, wol);

    sort3_kernel<<<dim3(BDIM, 3), 256, 0, stream>>>(wbc, wbm, wbf, sidx);

    // fused QKV projection (N = 3072), split-bf16 outputs
    dim3 g3(3 * EDIM / 128, MROWS / 128);   // (24, 64)
    gemm_qkv_kernel<<<g3, 256, 0, stream>>>(xh, xl, wh_all, wl_all,
                                            bq, bk, bv, qh, ql, kh, kl, vh);

    dim3 ga(NTOK / 128, BDIM * HEADS);  // (32, 32)
    attn_mfma_kernel<256><<<ga, 256, 0, stream>>>(qh, ql, kh, kl, vh, sidx + 0 * BDIM * NTOK, ab);
    attn_mfma_kernel<64><<<ga, 256, 0, stream>>>(qh, ql, kh, kl, vh, sidx + 1 * BDIM * NTOK, ab);
    attn_mfma_kernel<16><<<ga, 256, 0, stream>>>(qh, ql, kh, kl, vh, sidx + 2 * BDIM * NTOK, ab);

    // reuse xh/xl space for the attention-output split
    split_kernel<<<BNE / 1024, 256, 0, stream>>>(ab, xh, xl);
    dim3 gg(EDIM / 128, MROWS / 128);   // (8, 64)
    gemm_mfma_kernel<<<gg, 256, 0, stream>>>(xh, xl, woh, wol, bo, (float*)d_out);
}

// Round 6
// 592.684 us; speedup vs baseline: 4.0079x; 1.0489x over previous
//
#include <hip/hip_runtime.h>
#include <cstdint>
#include <cstddef>

// Problem constants
#define BDIM 2
#define NTOK 4096
#define EDIM 1024
#define HEADS 16
#define HDIM 64
#define MROWS (BDIM * NTOK)   // 8192

typedef unsigned short u16;
typedef __attribute__((ext_vector_type(8))) short bf16x8;   // 8 bf16 = 4 VGPR
typedef __attribute__((ext_vector_type(8))) unsigned short u16x8;
typedef __attribute__((ext_vector_type(4))) float f32x4;

#define MFMA(a, b, c) __builtin_amdgcn_mfma_f32_16x16x32_bf16(a, b, c, 0, 0, 0)

// round-to-nearest-even split of fp32 into hi/lo bf16
__device__ inline void split2(float x, u16& h, u16& l) {
    union { float f; unsigned u; } a;
    a.f = x;
    unsigned uh = a.u + 0x7fff + ((a.u >> 16) & 1);
    h = (u16)(uh >> 16);
    union { unsigned u; float f; } hf; hf.u = (unsigned)h << 16;
    a.f = x - hf.f;
    unsigned ul = a.u + 0x7fff + ((a.u >> 16) & 1);
    l = (u16)(ul >> 16);
}

__device__ inline u16 bf16rne(float x) {
    union { float f; unsigned u; } a; a.f = x;
    unsigned r = a.u + 0x7fff + ((a.u >> 16) & 1);
    return (u16)(r >> 16);
}

// global -> LDS direct 16B staging (lane i lands at lds_base + i*16)
#define GLL(gp, lp) __builtin_amdgcn_global_load_lds( \
    (const __attribute__((address_space(1))) unsigned*)(gp), \
    (__attribute__((address_space(3))) unsigned*)(lp), 16, 0, 0)

// ---------------------------------------------------------------------------
// W_eff = W + 2*B@A for all 4 projections in one launch. grid=(4096,4)
// ---------------------------------------------------------------------------
__global__ __launch_bounds__(256) void build_weff4_kernel(
    const float* __restrict__ W0, const float* __restrict__ A0, const float* __restrict__ B0,
    const float* __restrict__ W1, const float* __restrict__ A1, const float* __restrict__ B1,
    const float* __restrict__ W2, const float* __restrict__ A2, const float* __restrict__ B2,
    const float* __restrict__ W3, const float* __restrict__ A3, const float* __restrict__ B3,
    u16* __restrict__ dh0, u16* __restrict__ dl0,
    u16* __restrict__ dh1, u16* __restrict__ dl1,
    u16* __restrict__ dh2, u16* __restrict__ dl2,
    u16* __restrict__ dh3, u16* __restrict__ dl3)
{
    int s = blockIdx.y;
    const float* W = (s == 0) ? W0 : (s == 1) ? W1 : (s == 2) ? W2 : W3;
    const float* A = (s == 0) ? A0 : (s == 1) ? A1 : (s == 2) ? A2 : A3;
    const float* Bm = (s == 0) ? B0 : (s == 1) ? B1 : (s == 2) ? B2 : B3;
    u16* dh = (s == 0) ? dh0 : (s == 1) ? dh1 : (s == 2) ? dh2 : dh3;
    u16* dl = (s == 0) ? dl0 : (s == 1) ? dl1 : (s == 2) ? dl2 : dl3;

    int idx = blockIdx.x * 256 + threadIdx.x;      // over E*E
    int o = idx >> 10, i = idx & 1023;
    float sum = 0.f;
#pragma unroll
    for (int r = 0; r < 8; ++r) sum += Bm[o * 8 + r] * A[r * 1024 + i];
    float w = W[idx] + 2.0f * sum;
    u16 h, l;
    split2(w, h, l);
    dh[idx] = h; dl[idx] = l;
}

// ---------------------------------------------------------------------------
// fp32 buffer -> hi/lo bf16 buffers, 4 elements / thread
// ---------------------------------------------------------------------------
__global__ __launch_bounds__(256) void split_kernel(
    const float* __restrict__ src, u16* __restrict__ dh, u16* __restrict__ dl)
{
    int idx = blockIdx.x * 256 + threadIdx.x;      // one float4
    float4 v = ((const float4*)src)[idx];
    ushort4 h, l;
    split2(v.x, h.x, l.x);
    split2(v.y, h.y, l.y);
    split2(v.z, h.z, l.z);
    split2(v.w, h.w, l.w);
    ((ushort4*)dh)[idx] = h;
    ((ushort4*)dl)[idx] = l;
}

// ---------------------------------------------------------------------------
// Parallel stable counting sort, 3 scales x BDIM batches. grid=(BDIM,3).
// ---------------------------------------------------------------------------
__global__ __launch_bounds__(256) void sort3_kernel(
    const int* __restrict__ w0, const int* __restrict__ w1,
    const int* __restrict__ w2, int* __restrict__ sidx)
{
    __shared__ int sb[NTOK];          // 16 KB
    __shared__ int cnt[32][256];      // 32 KB
    __shared__ int gb[256];           // 1 KB
    const int* srcs[3] = {w0, w1, w2};
    int t = threadIdx.x;
    const int* w = srcs[blockIdx.y] + blockIdx.x * NTOK;
    int* outp = sidx + ((int)blockIdx.y * BDIM + (int)blockIdx.x) * NTOK;

    for (int i = t; i < NTOK; i += 256) sb[i] = w[i];
    for (int i = t; i < 32 * 256; i += 256) ((int*)cnt)[i] = 0;
    __syncthreads();

    int g = t >> 3;
#pragma unroll
    for (int e = 0; e < 16; ++e)
        atomicAdd(&cnt[g][sb[g * 128 + (t & 7) + 8 * e]], 1);
    __syncthreads();

    int run = 0;
#pragma unroll
    for (int gg = 0; gg < 32; ++gg) {
        int c = cnt[gg][t];
        cnt[gg][t] = run;
        run += c;
    }
    gb[t] = run;
    __syncthreads();
    if (t == 0) {
        int acc = 0;
        for (int v = 0; v < 256; ++v) { int c = gb[v]; gb[v] = acc; acc += c; }
    }
    __syncthreads();
    for (int i = t; i < 32 * 256; i += 256) {
        int v = i & 255, gg = i >> 8;
        cnt[gg][v] += gb[v];
    }
    __syncthreads();

    if (t < 32) {
        int base = t * 128;
        for (int e = 0; e < 128; ++e) {
            int v = sb[base + e];
            int p = cnt[t][v]++;
            outp[p] = base + e;
        }
    }
}

// ---------------------------------------------------------------------------
// Fused QKV split-bf16 MFMA GEMM: N = 3072 (Wh/Wl = [wq|wk|wv] stacked).
// Q -> (qh*0.125, ql), K -> (kh,kl): 3 MFMA passes. V -> vh only: 1 pass
// (hi*hi), half staging. Epilogue: LDS repack -> coalesced 16B u16x8 stores.
// grid = (3072/128, MROWS/128)
// ---------------------------------------------------------------------------
__global__ __launch_bounds__(256) void gemm_qkv_kernel(
    const u16* __restrict__ Xh, const u16* __restrict__ Xl,
    const u16* __restrict__ Wh, const u16* __restrict__ Wl,
    const float* __restrict__ bq, const float* __restrict__ bk,
    const float* __restrict__ bv,
    u16* __restrict__ qh, u16* __restrict__ ql,
    u16* __restrict__ kh, u16* __restrict__ kl, u16* __restrict__ vh)
{
    // union: staging (32768 B) / epilogue repack (4 waves x 32 x 68 fp32 = 34816 B)
    __shared__ __align__(16) unsigned char smem[34816];
    u16* lds = (u16*)smem;
    u16* ldsAh = lds;
    u16* ldsAl = lds + 4096;
    u16* ldsBh = lds + 8192;
    u16* ldsBl = lds + 12288;
    int t = threadIdx.x;
    int lane = t & 63, wave = t >> 6;
    int m0 = blockIdx.y * 128, n0 = blockIdx.x * 128;
    const bool isV = (n0 >= 2048);          // block-uniform
    int wm = (wave & 1) * 64, wn = (wave >> 1) * 64;
    f32x4 acc[4][4] = {};

    for (int kt = 0; kt < EDIM; kt += 32) {
        __syncthreads();
#pragma unroll
        for (int it = 0; it < 2; ++it) {
            int g = wave * 128 + it * 64 + lane;
            int row = ((g >> 6) << 4) | (g & 15);
            int kcol = kt + ((g >> 4) & 3) * 8;
            int lo = (wave * 128 + it * 64) * 8;
            GLL(Xh + (size_t)(m0 + row) * EDIM + kcol, ldsAh + lo);
            GLL(Wh + (size_t)(n0 + row) * EDIM + kcol, ldsBh + lo);
            if (!isV) {
                GLL(Xl + (size_t)(m0 + row) * EDIM + kcol, ldsAl + lo);
                GLL(Wl + (size_t)(n0 + row) * EDIM + kcol, ldsBl + lo);
            }
        }
        __syncthreads();

        int sA = wm >> 4, sB = wn >> 4;
        bf16x8 ah[4], al[4], bh[4], bl[4];
#pragma unroll
        for (int i = 0; i < 4; ++i) {
            ah[i] = *(const bf16x8*)(ldsAh + ((sA + i) * 64 + lane) * 8);
            bh[i] = *(const bf16x8*)(ldsBh + ((sB + i) * 64 + lane) * 8);
        }
        if (!isV) {
#pragma unroll
            for (int i = 0; i < 4; ++i) {
                al[i] = *(const bf16x8*)(ldsAl + ((sA + i) * 64 + lane) * 8);
                bl[i] = *(const bf16x8*)(ldsBl + ((sB + i) * 64 + lane) * 8);
            }
        }
#pragma unroll
        for (int i = 0; i < 4; ++i)
#pragma unroll
            for (int j = 0; j < 4; ++j) {
                acc[i][j] = MFMA(ah[i], bh[j], acc[i][j]);
                if (!isV) {
                    acc[i][j] = MFMA(ah[i], bl[j], acc[i][j]);
                    acc[i][j] = MFMA(al[i], bh[j], acc[i][j]);
                }
            }
    }
    __syncthreads();          // staging region now free for repack

    // ---- epilogue: per-wave LDS repack -> coalesced u16x8 stores ----
    int q4 = lane >> 4, l16 = lane & 15;
    int proj = n0 >> 10;                    // 0=Q, 1=K, 2=V
    const float* bias = (proj == 0) ? bq : (proj == 1) ? bk : bv;
    u16* oh = (proj == 0) ? qh : kh;
    u16* ol = (proj == 0) ? ql : kl;
    int cb = (n0 & 1023) + wn;
    float bj[4];
#pragma unroll
    for (int j = 0; j < 4; ++j) bj[j] = bias[cb + j * 16 + l16];

    float* repw = (float*)smem + wave * 2176;   // 32 rows x stride 68
    int r8 = lane >> 3, c8 = lane & 7;
#pragma unroll
    for (int half = 0; half < 2; ++half) {
        // phase A: deposit C-layout values (stride 68 -> 2-way, free)
#pragma unroll
        for (int ii = 0; ii < 2; ++ii)
#pragma unroll
            for (int j = 0; j < 4; ++j)
#pragma unroll
                for (int r = 0; r < 4; ++r)
                    repw[(ii * 16 + q4 * 4 + r) * 68 + j * 16 + l16] =
                        acc[half * 2 + ii][j][r] + bj[j];
        // phase B: 8 lanes/row -> contiguous 128B spans (sector-clean)
#pragma unroll
        for (int rg = 0; rg < 4; ++rg) {
            int lr = rg * 8 + r8;
            float4 f0 = *(float4*)(repw + lr * 68 + c8 * 8);
            float4 f1 = *(float4*)(repw + lr * 68 + c8 * 8 + 4);
            float fa[8] = {f0.x, f0.y, f0.z, f0.w, f1.x, f1.y, f1.z, f1.w};
            size_t off = (size_t)(m0 + wm + half * 32 + lr) * EDIM + cb + c8 * 8;
            if (isV) {
                u16x8 hv;
#pragma unroll
                for (int e = 0; e < 8; ++e) hv[e] = bf16rne(fa[e]);
                *(u16x8*)(vh + off) = hv;
            } else {
                u16x8 hv, lv;
#pragma unroll
                for (int e = 0; e < 8; ++e) {
                    float v = fa[e];
                    if (proj == 0) v *= 0.125f;
                    u16 hh, ll;
                    split2(v, hh, ll);
                    hv[e] = hh; lv[e] = ll;
                }
                *(u16x8*)(oh + off) = hv;
                *(u16x8*)(ol + off) = lv;
            }
        }
    }
}

// ---------------------------------------------------------------------------
// Split-bf16 MFMA GEMM (NT), fp32 out — used for the final O projection.
// ---------------------------------------------------------------------------
__global__ __launch_bounds__(256) void gemm_mfma_kernel(
    const u16* __restrict__ Xh, const u16* __restrict__ Xl,
    const u16* __restrict__ Wh, const u16* __restrict__ Wl,
    const float* __restrict__ bias, float* __restrict__ Y)
{
    __shared__ u16 lds[4 * 4096];
    u16* ldsAh = lds;
    u16* ldsAl = lds + 4096;
    u16* ldsBh = lds + 8192;
    u16* ldsBl = lds + 12288;
    int t = threadIdx.x;
    int lane = t & 63, wave = t >> 6;
    int m0 = blockIdx.y * 128, n0 = blockIdx.x * 128;
    int wm = (wave & 1) * 64, wn = (wave >> 1) * 64;
    f32x4 acc[4][4] = {};

    for (int kt = 0; kt < EDIM; kt += 32) {
        __syncthreads();
#pragma unroll
        for (int it = 0; it < 2; ++it) {
            int g = wave * 128 + it * 64 + lane;
            int row = ((g >> 6) << 4) | (g & 15);
            int kcol = kt + ((g >> 4) & 3) * 8;
            int lo = (wave * 128 + it * 64) * 8;
            GLL(Xh + (size_t)(m0 + row) * EDIM + kcol, ldsAh + lo);
            GLL(Xl + (size_t)(m0 + row) * EDIM + kcol, ldsAl + lo);
            GLL(Wh + (size_t)(n0 + row) * EDIM + kcol, ldsBh + lo);
            GLL(Wl + (size_t)(n0 + row) * EDIM + kcol, ldsBl + lo);
        }
        __syncthreads();

        int sA = wm >> 4, sB = wn >> 4;
        bf16x8 ah[4], al[4], bh[4], bl[4];
#pragma unroll
        for (int i = 0; i < 4; ++i) {
            ah[i] = *(const bf16x8*)(ldsAh + ((sA + i) * 64 + lane) * 8);
            al[i] = *(const bf16x8*)(ldsAl + ((sA + i) * 64 + lane) * 8);
            bh[i] = *(const bf16x8*)(ldsBh + ((sB + i) * 64 + lane) * 8);
            bl[i] = *(const bf16x8*)(ldsBl + ((sB + i) * 64 + lane) * 8);
        }
#pragma unroll
        for (int i = 0; i < 4; ++i)
#pragma unroll
            for (int j = 0; j < 4; ++j) {
                acc[i][j] = MFMA(ah[i], bh[j], acc[i][j]);
                acc[i][j] = MFMA(ah[i], bl[j], acc[i][j]);
                acc[i][j] = MFMA(al[i], bh[j], acc[i][j]);
            }
    }

    int col_in = lane & 15, rquad = lane >> 4;
#pragma unroll
    for (int j = 0; j < 4; ++j) {
        int col = n0 + wn + j * 16 + col_in;
        float bv = bias[col];
#pragma unroll
        for (int i = 0; i < 4; ++i) {
            int mbase = m0 + wm + i * 16 + rquad * 4;
#pragma unroll
            for (int r = 0; r < 4; ++r)
                Y[(size_t)(mbase + r) * EDIM + col] = acc[i][j][r] + bv;
        }
    }
}

// ---------------------------------------------------------------------------
// MFMA flash attention v2. Inputs pre-split bf16 (qh scaled, kh/kl, vh).
// ---------------------------------------------------------------------------
template <int C>
__global__ __launch_bounds__(256, 3) void attn_mfma_kernel(
    const u16* __restrict__ Qh, const u16* __restrict__ Ql,
    const u16* __restrict__ Kh, const u16* __restrict__ Kl,
    const u16* __restrict__ Vh, const int* __restrict__ sidx,
    float* __restrict__ out)
{
    __shared__ u16 KfH[4096], KfL[4096];   // [s(4)][kk(2)][lane(64)][8]
    __shared__ u16 VL[64 * 72];            // [dim(64)][key(64)] stride 72
    __shared__ u16 PbH[4 * 16 * 56];       // per-wave P, row stride 56

    int t = threadIdx.x;
    int lane = t & 63, wave = t >> 6;
    int quad = lane >> 4, l16 = lane & 15;
    int bh = blockIdx.y, b = bh >> 4, h = bh & 15;
    int p0 = blockIdx.x * 128;
    const int* sxb = sidx + b * NTOK;

    int ptile[2], ws_[2], we_[2];
    bf16x8 qhf[2][2], qlf[2][2];
#pragma unroll
    for (int tq = 0; tq < 2; ++tq) {
        ptile[tq] = p0 + wave * 32 + tq * 16;
        int c = ptile[tq] / C;
        ws_[tq] = (c > 0) ? (c - 1) * C : 0;
        we_[tq] = (c + 1) * C;
        int qrow = sxb[ptile[tq] + l16];
        size_t rb = (size_t)(b * NTOK + qrow) * EDIM + h * HDIM + quad * 8;
#pragma unroll
        for (int kk = 0; kk < 2; ++kk) {
            qhf[tq][kk] = *(const bf16x8*)(Qh + rb + kk * 32);
            qlf[tq][kk] = *(const bf16x8*)(Ql + rb + kk * 32);
        }
    }

    f32x4 oacc[2][4] = {};
    float lpart[2][4] = {};
    float mrun[2] = {-1e30f, -1e30f};

    int c0 = p0 / C, c1 = (p0 + 127) / C;
    int kmin = (c0 > 0) ? (c0 - 1) * C : 0;
    int kmax = (c1 + 1) * C;

    for (int ks = kmin; ks < kmax; ks += 64) {
        int nk = min(64, kmax - ks);
        __syncthreads();

        {
            int key16 = lane & 15, qd = lane >> 4;
            int tok = sxb[min(ks + wave * 16 + key16, NTOK - 1)];
            size_t rb = (size_t)(b * NTOK + tok) * EDIM + h * HDIM + qd * 8;
            GLL(Kh + rb,      KfH + (wave * 2 + 0) * 512);
            GLL(Kh + rb + 32, KfH + (wave * 2 + 1) * 512);
            GLL(Kl + rb,      KfL + (wave * 2 + 0) * 512);
            GLL(Kl + rb + 32, KfL + (wave * 2 + 1) * 512);
        }
#pragma unroll
        for (int it = 0; it < 2; ++it) {
            int c = it * 256 + t;            // 0..511
            int key = c & 63, dg = c >> 6;
            int tok = sxb[min(ks + key, NTOK - 1)];
            bf16x8 vv = *(const bf16x8*)(Vh + (size_t)(b * NTOK + tok) * EDIM + h * HDIM + dg * 8);
#pragma unroll
            for (int e = 0; e < 8; ++e)
                VL[(dg * 8 + e) * 72 + key] = (u16)vv[e];
        }
        __syncthreads();

        int jlo0 = max(ks, ws_[0]) - ks, jhi0 = min(ks + nk, we_[0]) - ks;
        int jlo1 = max(ks, ws_[1]) - ks, jhi1 = min(ks + nk, we_[1]) - ks;
        bool e0 = jlo0 < jhi0, e1 = jlo1 < jhi1;
        if (!e0 && !e1) continue;
        int glo = e0 ? (e1 ? min(jlo0, jlo1) : jlo0) : jlo1;
        int ghi = e0 ? (e1 ? max(jhi0, jhi1) : jhi0) : jhi1;

        for (int g0 = glo & ~31; g0 < ghi; g0 += 32) {
            int s0i = g0 >> 4;
            int s1i = min(s0i + 1, 3);
            bf16x8 kh0[2], kl0[2], kh1[2], kl1[2];
#pragma unroll
            for (int kk = 0; kk < 2; ++kk) {
                kh0[kk] = *(const bf16x8*)(KfH + ((s0i * 2 + kk) * 64 + lane) * 8);
                kl0[kk] = *(const bf16x8*)(KfL + ((s0i * 2 + kk) * 64 + lane) * 8);
                kh1[kk] = *(const bf16x8*)(KfH + ((s1i * 2 + kk) * 64 + lane) * 8);
                kl1[kk] = *(const bf16x8*)(KfL + ((s1i * 2 + kk) * 64 + lane) * 8);
            }
#pragma unroll
            for (int tq = 0; tq < 2; ++tq) {
                int jl = tq ? jlo1 : jlo0, jh = tq ? jhi1 : jhi0;
                bool v0 = (g0 >= jl) && (g0 < jh);
                bool v1 = (g0 + 16 >= jl) && (g0 + 16 < jh);
                if (!v0 && !v1) continue;
                f32x4 sa = {0.f, 0.f, 0.f, 0.f}, sb2 = {0.f, 0.f, 0.f, 0.f};
                if (v0) {
                    sa = MFMA(qhf[tq][0], kh0[0], sa);
                    sa = MFMA(qhf[tq][0], kl0[0], sa);
                    sa = MFMA(qlf[tq][0], kh0[0], sa);
                    sa = MFMA(qhf[tq][1], kh0[1], sa);
                    sa = MFMA(qhf[tq][1], kl0[1], sa);
                    sa = MFMA(qlf[tq][1], kh0[1], sa);
                }
                if (v1) {
                    sb2 = MFMA(qhf[tq][0], kh1[0], sb2);
                    sb2 = MFMA(qhf[tq][0], kl1[0], sb2);
                    sb2 = MFMA(qlf[tq][0], kh1[0], sb2);
                    sb2 = MFMA(qhf[tq][1], kh1[1], sb2);
                    sb2 = MFMA(qhf[tq][1], kl1[1], sb2);
                    sb2 = MFMA(qlf[tq][1], kh1[1], sb2);
                }
                float smax = -1e30f;
                if (v0) smax = fmaxf(smax, fmaxf(fmaxf(sa[0], sa[1]), fmaxf(sa[2], sa[3])));
                if (v1) smax = fmaxf(smax, fmaxf(fmaxf(sb2[0], sb2[1]), fmaxf(sb2[2], sb2[3])));
                smax = fmaxf(smax, __shfl_xor(smax, 1));
                smax = fmaxf(smax, __shfl_xor(smax, 2));
                smax = fmaxf(smax, __shfl_xor(smax, 4));
                smax = fmaxf(smax, __shfl_xor(smax, 8));
                float mold = mrun[tq];
                float mnew = fmaxf(mold, smax);
                mrun[tq] = mnew;
                float alpha = __expf(mold - mnew);
#pragma unroll
                for (int r = 0; r < 4; ++r) lpart[tq][r] *= alpha;
#pragma unroll
                for (int dt = 0; dt < 4; ++dt) {
                    oacc[tq][dt][0] *= alpha; oacc[tq][dt][1] *= alpha;
                    oacc[tq][dt][2] *= alpha; oacc[tq][dt][3] *= alpha;
                }
                u16* pbh = PbH + wave * 896;
#pragma unroll
                for (int r = 0; r < 4; ++r) {
                    float pa = v0 ? __expf(sa[r] - mnew) : 0.f;
                    float pb = v1 ? __expf(sb2[r] - mnew) : 0.f;
                    lpart[tq][r] += pa + pb;
                    pbh[(quad * 4 + r) * 56 + l16] = bf16rne(pa);
                    pbh[(quad * 4 + r) * 56 + 16 + l16] = bf16rne(pb);
                }
                bf16x8 ph = *(const bf16x8*)(pbh + l16 * 56 + quad * 8);
                int kh2 = g0 >> 5;
#pragma unroll
                for (int dt = 0; dt < 4; ++dt) {
                    bf16x8 vv = *(const bf16x8*)(VL + (dt * 16 + l16) * 72 + kh2 * 32 + quad * 8);
                    oacc[tq][dt] = MFMA(ph, vv, oacc[tq][dt]);
                }
            }
        }
    }

#pragma unroll
    for (int tq = 0; tq < 2; ++tq) {
        float inv[4];
#pragma unroll
        for (int r = 0; r < 4; ++r) {
            float v = lpart[tq][r];
            v += __shfl_xor(v, 1);
            v += __shfl_xor(v, 2);
            v += __shfl_xor(v, 4);
            v += __shfl_xor(v, 8);
            inv[r] = 1.0f / (3.0f * v);
        }
#pragma unroll
        for (int r = 0; r < 4; ++r) {
            int tok = sxb[ptile[tq] + quad * 4 + r];
            float* op = out + (size_t)(b * NTOK + tok) * EDIM + h * HDIM + l16;
#pragma unroll
            for (int dt = 0; dt < 4; ++dt)
                op[dt * 16] += oacc[tq][dt][r] * inv[r];
        }
    }
}

// ---------------------------------------------------------------------------
extern "C" void kernel_launch(void* const* d_in, const int* in_sizes, int n_in,
                              void* d_out, int out_size, void* d_ws, size_t ws_size,
                              hipStream_t stream)
{
    const float* x   = (const float*)d_in[0];
    const int*   wbc = (const int*)d_in[1];
    const int*   wbm = (const int*)d_in[2];
    const int*   wbf = (const int*)d_in[3];
    const float* Wq = (const float*)d_in[4],  *bq = (const float*)d_in[5];
    const float* Aq = (const float*)d_in[6],  *Bq = (const float*)d_in[7];
    const float* Wk = (const float*)d_in[8],  *bk = (const float*)d_in[9];
    const float* Ak = (const float*)d_in[10], *Bk = (const float*)d_in[11];
    const float* Wv = (const float*)d_in[12], *bv = (const float*)d_in[13];
    const float* Av = (const float*)d_in[14], *Bv = (const float*)d_in[15];
    const float* Wo = (const float*)d_in[16], *bo = (const float*)d_in[17];
    const float* Ao = (const float*)d_in[18], *Bo = (const float*)d_in[19];

    const size_t EE  = (size_t)EDIM * EDIM;        // 1,048,576
    const size_t BNE = (size_t)MROWS * EDIM;       // 8,388,608

    char* wsb = (char*)d_ws;
    float* ab = (float*)wsb;                        wsb += BNE * 4;   // attn accum
    u16* xh = (u16*)wsb;                            wsb += BNE * 2;   // also abh
    u16* xl = (u16*)wsb;                            wsb += BNE * 2;   // also abl
    u16* qh = (u16*)wsb;                            wsb += BNE * 2;
    u16* ql = (u16*)wsb;                            wsb += BNE * 2;
    u16* kh = (u16*)wsb;                            wsb += BNE * 2;
    u16* kl = (u16*)wsb;                            wsb += BNE * 2;
    u16* vh = (u16*)wsb;                            wsb += BNE * 2;
    u16* wh_all = (u16*)wsb;                        wsb += 3 * EE * 2; // [q|k|v] hi
    u16* wl_all = (u16*)wsb;                        wsb += 3 * EE * 2; // [q|k|v] lo
    u16* woh = (u16*)wsb;                           wsb += EE * 2;
    u16* wol = (u16*)wsb;                           wsb += EE * 2;
    int* sidx = (int*)wsb;                          wsb += 3 * BDIM * NTOK * 4;

    // attention accumulator must start at zero (ws is poisoned each call)
    hipMemsetAsync(ab, 0, BNE * sizeof(float), stream);

    split_kernel<<<BNE / 1024, 256, 0, stream>>>(x, xh, xl);

    build_weff4_kernel<<<dim3(4096, 4), 256, 0, stream>>>(
        Wq, Aq, Bq, Wk, Ak, Bk, Wv, Av, Bv, Wo, Ao, Bo,
        wh_all + 0 * EE, wl_all + 0 * EE,
        wh_all + 1 * EE, wl_all + 1 * EE,
        wh_all + 2 * EE, wl_all + 2 * EE,
        woh, wol);

    sort3_kernel<<<dim3(BDIM, 3), 256, 0, stream>>>(wbc, wbm, wbf, sidx);

    // fused QKV projection (N = 3072), split-bf16 outputs
    dim3 g3(3 * EDIM / 128, MROWS / 128);   // (24, 64)
    gemm_qkv_kernel<<<g3, 256, 0, stream>>>(xh, xl, wh_all, wl_all,
                                            bq, bk, bv, qh, ql, kh, kl, vh);

    dim3 ga(NTOK / 128, BDIM * HEADS);  // (32, 32)
    attn_mfma_kernel<256><<<ga, 256, 0, stream>>>(qh, ql, kh, kl, vh, sidx + 0 * BDIM * NTOK, ab);
    attn_mfma_kernel<64><<<ga, 256, 0, stream>>>(qh, ql, kh, kl, vh, sidx + 1 * BDIM * NTOK, ab);
    attn_mfma_kernel<16><<<ga, 256, 0, stream>>>(qh, ql, kh, kl, vh, sidx + 2 * BDIM * NTOK, ab);

    // reuse xh/xl space for the attention-output split
    split_kernel<<<BNE / 1024, 256, 0, stream>>>(ab, xh, xl);
    dim3 gg(EDIM / 128, MROWS / 128);   // (8, 64)
    gemm_mfma_kernel<<<gg, 256, 0, stream>>>(xh, xl, woh, wol, bo, (float*)d_out);
}